// Round 5
// baseline (119.116 us; speedup 1.0000x reference)
//
#include <hip/hip_runtime.h>

typedef __attribute__((ext_vector_type(8))) short short8;
typedef __attribute__((ext_vector_type(4))) short short4v;
typedef __attribute__((ext_vector_type(4))) float f32x4;

__device__ __forceinline__ float bf2f(short s) {
  union { unsigned u; float f; } cv;
  cv.u = ((unsigned)(unsigned short)s) << 16;
  return cv.f;
}
__device__ __forceinline__ short f2bf(float f) {
  union { float f; unsigned u; } cv;
  cv.f = f;
  unsigned r = (cv.u + 0x7fffu + ((cv.u >> 16) & 1u)) >> 16;
  return (short)(unsigned short)r;
}

#define MFMA16(a, b, c) __builtin_amdgcn_mfma_f32_16x16x32_bf16((a), (b), (c), 0, 0, 0)

// ---------------------------------------------------------------------------
// convert fp32 weight matrices -> bf16 workspace. 4 matrices x 32768 elems.
// ---------------------------------------------------------------------------
__global__ __launch_bounds__(256) void cvt_w(
    const float* __restrict__ s0, const float* __restrict__ s1,
    const float* __restrict__ s2, const float* __restrict__ s3,
    short* __restrict__ d)
{
  const float* srcs[4] = {s0, s1, s2, s3};
  const float* s = srcs[blockIdx.y];
  int i = (blockIdx.x * 256 + threadIdx.x) * 4;
  f32x4 v = *reinterpret_cast<const f32x4*>(s + i);
  short4v o;
  #pragma unroll
  for (int j = 0; j < 4; j++) o[j] = f2bf(v[j]);
  *reinterpret_cast<short4v*>(d + (size_t)blockIdx.y * 32768 + i) = o;
}

// ---------------------------------------------------------------------------
// conv1x1: out[b][p][o] = sum_c in[b][c][p] * w[o][c] + bias[o]
// in: fp32 [b][c][4096]; w: bf16 [o][256] (pre-converted); out: bf16 [b][p][o]
// ---------------------------------------------------------------------------
template <int NPROJ>
__global__ __launch_bounds__(256) void conv_proj(
    const float* __restrict__ in,
    const short* __restrict__ w0, const float* __restrict__ bias0,
    const short* __restrict__ w1, const float* __restrict__ bias1,
    short* __restrict__ out0, short* __restrict__ out1)
{
  __shared__ short in_t[64][40];            // [p][c], octet-XOR swizzled
  __shared__ short wt[NPROJ][128][40];      // [o][c], octet-XOR swizzled

  const int b = blockIdx.y;
  const int p0 = blockIdx.x * 64;
  const int tid = threadIdx.x;
  const int wave = tid >> 6, lane = tid & 63;
  const int lr = lane & 15, lg = lane >> 4;

  const short* wsrc[2] = {w0, w1};

  f32x4 acc[NPROJ][8];
  #pragma unroll
  for (int pj = 0; pj < NPROJ; pj++)
    #pragma unroll
    for (int n = 0; n < 8; n++) acc[pj][n] = (f32x4)0.0f;

  for (int kc = 0; kc < 256; kc += 32) {
    __syncthreads();
    {
      int c = tid >> 3;                 // 0..31
      int pg = (tid & 7) * 8;           // pixel group
      const float* src = in + ((size_t)(b * 256 + kc + c)) * 4096 + p0 + pg;
      f32x4 v0 = *reinterpret_cast<const f32x4*>(src);
      f32x4 v1 = *reinterpret_cast<const f32x4*>(src + 4);
      #pragma unroll
      for (int j = 0; j < 8; j++) {
        int p = pg + j;
        float fv = (j < 4) ? v0[j] : v1[j - 4];
        in_t[p][c ^ ((((p >> 3) & 3)) << 3)] = f2bf(fv);
      }
    }
    for (int idx = tid; idx < NPROJ * 128; idx += 256) {
      int pj = idx >> 7, o = idx & 127;
      const short8* src = reinterpret_cast<const short8*>(wsrc[pj] + (size_t)o * 256 + kc);
      int f = (o >> 3) & 3;
      #pragma unroll
      for (int gq = 0; gq < 4; gq++)
        *reinterpret_cast<short8*>(&wt[pj][o][(gq ^ f) * 8]) = src[gq];
    }
    __syncthreads();

    int arow = wave * 16 + lr;
    short8 afrag = *reinterpret_cast<const short8*>(
        &in_t[arow][(lg ^ ((arow >> 3) & 3)) * 8]);
    #pragma unroll
    for (int pj = 0; pj < NPROJ; pj++) {
      #pragma unroll
      for (int n = 0; n < 8; n++) {
        int brow = n * 16 + lr;
        short8 bfrag = *reinterpret_cast<const short8*>(
            &wt[pj][brow][(lg ^ ((brow >> 3) & 3)) * 8]);
        acc[pj][n] = MFMA16(afrag, bfrag, acc[pj][n]);
      }
    }
  }

  const float* bsrc[2] = {bias0, bias1};
  short* osrc[2] = {out0, out1};
  #pragma unroll
  for (int pj = 0; pj < NPROJ; pj++) {
    #pragma unroll
    for (int n = 0; n < 8; n++) {
      int o = n * 16 + lr;
      float bv = bsrc[pj][o];
      #pragma unroll
      for (int r = 0; r < 4; r++) {
        int prow = p0 + wave * 16 + lg * 4 + r;
        osrc[pj][((size_t)b * 4096 + prow) * 128 + o] = f2bf(acc[pj][n][r] + bv);
      }
    }
  }
}

// ---------------------------------------------------------------------------
// maxpool 2x2: src bf16 [b][p=4096][128] -> dst bf16 [b][kp=1024][128]
// ---------------------------------------------------------------------------
__global__ __launch_bounds__(256) void pool_phi_k(const short* __restrict__ src,
                                                  short* __restrict__ dst)
{
  int b = blockIdx.y;
  int kp = blockIdx.x * 16 + (threadIdx.x >> 4);
  int o8 = (threadIdx.x & 15) * 8;
  int ph = kp >> 5, pw = kp & 31;
  size_t base = ((size_t)b * 4096 + ph * 128 + pw * 2) * 128 + o8;
  short8 v0 = *reinterpret_cast<const short8*>(src + base);
  short8 v1 = *reinterpret_cast<const short8*>(src + base + 128);
  short8 v2 = *reinterpret_cast<const short8*>(src + base + 64 * 128);
  short8 v3 = *reinterpret_cast<const short8*>(src + base + 65 * 128);
  short8 o;
  #pragma unroll
  for (int j = 0; j < 8; j++) {
    float m = fmaxf(fmaxf(bf2f(v0[j]), bf2f(v1[j])), fmaxf(bf2f(v2[j]), bf2f(v3[j])));
    o[j] = f2bf(m);
  }
  *reinterpret_cast<short8*>(dst + ((size_t)b * 1024 + kp) * 128 + o8) = o;
}

// ---------------------------------------------------------------------------
// maxpool 2x2 + transpose: src bf16 [b][p=4096][128] -> dst bf16 [b][128][kp=1024]
// ---------------------------------------------------------------------------
__global__ __launch_bounds__(256) void pool_g_t(const short* __restrict__ src,
                                                short* __restrict__ dst)
{
  __shared__ short s[32][136];
  int b = blockIdx.y;
  int kp0 = blockIdx.x * 32;
  int t = threadIdx.x;
  {
    int kpl = t >> 3;
    int o0 = (t & 7) * 16;
    int kp = kp0 + kpl;
    int ph = kp >> 5, pw = kp & 31;
    size_t base = ((size_t)b * 4096 + ph * 128 + pw * 2) * 128;
    #pragma unroll
    for (int h = 0; h < 2; h++) {
      int oo = o0 + h * 8;
      short8 v0 = *reinterpret_cast<const short8*>(src + base + oo);
      short8 v1 = *reinterpret_cast<const short8*>(src + base + 128 + oo);
      short8 v2 = *reinterpret_cast<const short8*>(src + base + 64 * 128 + oo);
      short8 v3 = *reinterpret_cast<const short8*>(src + base + 65 * 128 + oo);
      #pragma unroll
      for (int j = 0; j < 8; j++) {
        float m = fmaxf(fmaxf(bf2f(v0[j]), bf2f(v1[j])), fmaxf(bf2f(v2[j]), bf2f(v3[j])));
        s[kpl][oo + j] = f2bf(m);
      }
    }
  }
  __syncthreads();
  {
    int o = t >> 1;
    int k0 = (t & 1) * 16;
    short8 v0, v1;
    #pragma unroll
    for (int j = 0; j < 8; j++) { v0[j] = s[k0 + j][o]; v1[j] = s[k0 + 8 + j][o]; }
    *reinterpret_cast<short8*>(dst + ((size_t)b * 128 + o) * 1024 + kp0 + k0) = v0;
    *reinterpret_cast<short8*>(dst + ((size_t)b * 128 + o) * 1024 + kp0 + k0 + 8) = v1;
  }
}

// ---------------------------------------------------------------------------
// flash attention v4: split-KV x2. Grid (32 qtiles, 8 b, 2 kv-halves).
// QBLK=128 (4 waves x 32 q), KVBLK=64, 8 iters per block.
// Swapped QK^T, defer-rescale THR=10, exports unnormalized acc + (m,l).
// ---------------------------------------------------------------------------
__global__ __launch_bounds__(256) void attn_split(
    const short* __restrict__ theta, const short* __restrict__ phi,
    const short* __restrict__ g,
    short* __restrict__ pacc0, short* __restrict__ pacc1,
    float* __restrict__ pm, float* __restrict__ pl)
{
  __shared__ short phi_s[2][64][128];   // rows 256B = 16 slots, key = kv&15
  __shared__ short g_s[2][128][64];     // rows 128B = 8 slots,  key = ci&7
  __shared__ short p_s[4][32][64];      // per-wave, rows 128B,  key = q&7

  const int b = blockIdx.y;
  const int q0 = blockIdx.x * 128;
  const int z = blockIdx.z;
  const int tid = threadIdx.x;
  const int wave = tid >> 6, lane = tid & 63;
  const int lr = lane & 15, lg = lane >> 4;

  // theta fragments (32 q rows per wave: two 16-row halves)
  short8 ath[2][4];
  {
    const short* tq = theta + ((size_t)b * 4096 + q0 + wave * 32 + lr) * 128 + lg * 8;
    #pragma unroll
    for (int qh = 0; qh < 2; qh++)
      #pragma unroll
      for (int kk = 0; kk < 4; kk++)
        ath[qh][kk] = *reinterpret_cast<const short8*>(tq + qh * 16 * 128 + kk * 32);
  }

  // staging: thread covers 64B of phi tile and 64B of g tile (linear global)
  const int pr = tid >> 2, pcq = tid & 3;     // phi row 0..63, quarter
  const int gr = tid >> 1, ghq = tid & 1;     // g row 0..127, half
  const short* phi_src = phi + ((size_t)b * 1024 + z * 512 + pr) * 128 + pcq * 32;
  const short* g_src   = g + ((size_t)b * 128 + gr) * 1024 + z * 512 + ghq * 32;

  short8 sphi[4], sg[4];
  #pragma unroll
  for (int j = 0; j < 4; j++) {
    sphi[j] = *reinterpret_cast<const short8*>(phi_src + j * 8);
    sg[j]   = *reinterpret_cast<const short8*>(g_src + j * 8);
  }

  float mrun[2] = {-1e30f, -1e30f}, lpart[2] = {0.0f, 0.0f};
  f32x4 acc[2][8];
  #pragma unroll
  for (int qh = 0; qh < 2; qh++)
    #pragma unroll
    for (int n = 0; n < 8; n++) acc[qh][n] = (f32x4)0.0f;

  char* const pbase = (char*)&p_s[wave][0][0];
  const int pkey = (lr & 7) << 4;

  for (int t = 0; t < 8; t++) {
    char* phib = (char*)&phi_s[t & 1][0][0];
    char* gbse = (char*)&g_s[t & 1][0][0];
    // write staged tile t (swizzled slots)
    #pragma unroll
    for (int j = 0; j < 4; j++) {
      *reinterpret_cast<short8*>(phib + pr * 256 + (((pcq * 4 + j) ^ (pr & 15)) * 16)) = sphi[j];
      *reinterpret_cast<short8*>(gbse + gr * 128 + (((ghq * 4 + j) ^ (gr & 7)) * 16)) = sg[j];
    }
    __syncthreads();

    // issue loads for tile t+1
    if (t < 7) {
      const short* ps = phi_src + (t + 1) * 64 * 128;
      const short* gs = g_src + (t + 1) * 64;
      #pragma unroll
      for (int j = 0; j < 4; j++) {
        sphi[j] = *reinterpret_cast<const short8*>(ps + j * 8);
        sg[j]   = *reinterpret_cast<const short8*>(gs + j * 8);
      }
    }

    // QK^T swapped: facc[qh][n] = S^T tile [kv=16n..][q=qh*16..]
    f32x4 facc[2][4];
    #pragma unroll
    for (int qh = 0; qh < 2; qh++)
      #pragma unroll
      for (int n = 0; n < 4; n++) facc[qh][n] = (f32x4)0.0f;
    #pragma unroll
    for (int kk = 0; kk < 4; kk++) {
      #pragma unroll
      for (int n = 0; n < 4; n++) {
        int row = n * 16 + lr;
        short8 pf = *reinterpret_cast<const short8*>(
            phib + row * 256 + (((4 * kk + lg) ^ (row & 15)) * 16));
        facc[0][n] = MFMA16(pf, ath[0][kk], facc[0][n]);
        facc[1][n] = MFMA16(pf, ath[1][kk], facc[1][n]);
      }
    }

    // online softmax with defer-rescale (THR=10): lane owns q = qh*16+lr
    float pmax[2];
    #pragma unroll
    for (int qh = 0; qh < 2; qh++) {
      float m0 = fmaxf(fmaxf(facc[qh][0][0], facc[qh][0][1]), fmaxf(facc[qh][0][2], facc[qh][0][3]));
      float m1 = fmaxf(fmaxf(facc[qh][1][0], facc[qh][1][1]), fmaxf(facc[qh][1][2], facc[qh][1][3]));
      float m2 = fmaxf(fmaxf(facc[qh][2][0], facc[qh][2][1]), fmaxf(facc[qh][2][2], facc[qh][2][3]));
      float m3 = fmaxf(fmaxf(facc[qh][3][0], facc[qh][3][1]), fmaxf(facc[qh][3][2], facc[qh][3][3]));
      float m = fmaxf(fmaxf(m0, m1), fmaxf(m2, m3));
      m = fmaxf(m, __shfl_xor(m, 16));
      m = fmaxf(m, __shfl_xor(m, 32));
      pmax[qh] = m;
    }
    bool need = (pmax[0] - mrun[0] > 10.0f) | (pmax[1] - mrun[1] > 10.0f);
    if (__any(need)) {
      float mn0 = fmaxf(mrun[0], pmax[0]);
      float mn1 = fmaxf(mrun[1], pmax[1]);
      float sc0 = __expf(mrun[0] - mn0);
      float sc1 = __expf(mrun[1] - mn1);
      mrun[0] = mn0; mrun[1] = mn1;
      lpart[0] *= sc0; lpart[1] *= sc1;
      #pragma unroll
      for (int r = 0; r < 4; r++) {
        float s0 = __shfl(sc0, lg * 4 + r);
        float s1 = __shfl(sc1, lg * 4 + r);
        #pragma unroll
        for (int n = 0; n < 8; n++) { acc[0][n][r] *= s0; acc[1][n][r] *= s1; }
      }
    }
    // P = exp(S - m): pack 4 kv values -> one b64 write per (qh, n)
    #pragma unroll
    for (int qh = 0; qh < 2; qh++) {
      #pragma unroll
      for (int n = 0; n < 4; n++) {
        float e0 = __expf(facc[qh][n][0] - mrun[qh]);
        float e1 = __expf(facc[qh][n][1] - mrun[qh]);
        float e2 = __expf(facc[qh][n][2] - mrun[qh]);
        float e3 = __expf(facc[qh][n][3] - mrun[qh]);
        lpart[qh] += (e0 + e1) + (e2 + e3);
        short4v pk;
        pk[0] = f2bf(e0); pk[1] = f2bf(e1); pk[2] = f2bf(e2); pk[3] = f2bf(e3);
        *reinterpret_cast<short4v*>(
            pbase + (qh * 16 + lr) * 128 + ((n * 32 + lg * 8) ^ pkey)) = pk;
      }
    }

    // y^T accumulate: acc[qh][n] += P[qh] . g  (A from p_s, B from g_s)
    #pragma unroll
    for (int kk = 0; kk < 2; kk++) {
      short8 pa0 = *reinterpret_cast<const short8*>(
          pbase + lr * 128 + ((kk * 64 + lg * 16) ^ pkey));
      short8 pa1 = *reinterpret_cast<const short8*>(
          pbase + (16 + lr) * 128 + ((kk * 64 + lg * 16) ^ pkey));
      #pragma unroll
      for (int n = 0; n < 8; n++) {
        int row = n * 16 + lr;
        short8 gf = *reinterpret_cast<const short8*>(
            gbse + row * 128 + (((4 * kk + lg) ^ (row & 7)) * 16));
        acc[0][n] = MFMA16(pa0, gf, acc[0][n]);
        acc[1][n] = MFMA16(pa1, gf, acc[1][n]);
      }
    }
    __syncthreads();
  }

  // export (m, l) per q and unnormalized partial acc
  float lsum[2];
  #pragma unroll
  for (int qh = 0; qh < 2; qh++) {
    float s = lpart[qh];
    s += __shfl_xor(s, 16);
    s += __shfl_xor(s, 32);
    lsum[qh] = s;
  }
  if (lane < 16) {
    #pragma unroll
    for (int qh = 0; qh < 2; qh++) {
      int q = q0 + wave * 32 + qh * 16 + lr;
      pm[z * 32768 + b * 4096 + q] = mrun[qh];
      pl[z * 32768 + b * 4096 + q] = lsum[qh];
    }
  }
  short* pacc = z ? pacc1 : pacc0;
  #pragma unroll
  for (int qh = 0; qh < 2; qh++) {
    #pragma unroll
    for (int n = 0; n < 8; n++) {
      #pragma unroll
      for (int r = 0; r < 4; r++) {
        int q = q0 + wave * 32 + qh * 16 + lg * 4 + r;
        pacc[((size_t)b * 4096 + q) * 128 + n * 16 + lr] = f2bf(acc[qh][n][r]);
      }
    }
  }
}

// ---------------------------------------------------------------------------
// merge two KV-half partials: y = (w0*a0 + w1*a1) / (w0*l0 + w1*l1)
// ---------------------------------------------------------------------------
__global__ __launch_bounds__(256) void attn_merge(
    const short* __restrict__ a0, const short* __restrict__ a1,
    const float* __restrict__ pm, const float* __restrict__ pl,
    short* __restrict__ y)
{
  int b = blockIdx.y;
  int q = blockIdx.x * 16 + (threadIdx.x >> 4);
  int c8 = (threadIdx.x & 15) * 8;
  int iq = b * 4096 + q;
  float m0 = pm[iq], m1 = pm[32768 + iq];
  float l0 = pl[iq], l1 = pl[32768 + iq];
  float M = fmaxf(m0, m1);
  float w0 = __expf(m0 - M), w1 = __expf(m1 - M);
  float inv = 1.0f / (w0 * l0 + w1 * l1);
  w0 *= inv; w1 *= inv;
  size_t base = (size_t)iq * 128 + c8;
  short8 A0 = *reinterpret_cast<const short8*>(a0 + base);
  short8 A1 = *reinterpret_cast<const short8*>(a1 + base);
  short8 o;
  #pragma unroll
  for (int j = 0; j < 8; j++)
    o[j] = f2bf(w0 * bf2f(A0[j]) + w1 * bf2f(A1[j]));
  *reinterpret_cast<short8*>(y + base) = o;
}

// ---------------------------------------------------------------------------
// wy = w_w . y (per pixel) + bias, BN (eval), + x  -> out fp32 [b][256][4096]
// ---------------------------------------------------------------------------
__global__ __launch_bounds__(256) void wconv_bn(
    const short* __restrict__ y, const short* __restrict__ ww,
    const float* __restrict__ wb,
    const float* __restrict__ gamma, const float* __restrict__ beta,
    const float* __restrict__ mean, const float* __restrict__ var,
    const float* __restrict__ x, float* __restrict__ out)
{
  __shared__ short y_s[64][136];
  __shared__ float sc_s[256];
  __shared__ float sh_s[256];

  const int b = blockIdx.y;
  const int q0 = blockIdx.x * 64;
  const int tid = threadIdx.x;
  const int wave = tid >> 6, lane = tid & 63;
  const int lr = lane & 15, lg = lane >> 4;

  {
    int r = tid >> 2, c0 = (tid & 3) * 32;
    const short8* src = reinterpret_cast<const short8*>(
        y + ((size_t)b * 4096 + q0 + r) * 128 + c0);
    short8* dstv = reinterpret_cast<short8*>(&y_s[r][c0]);
    #pragma unroll
    for (int j = 0; j < 4; j++) dstv[j] = src[j];
    float s = gamma[tid] * rsqrtf(var[tid] + 1e-5f);
    sc_s[tid] = s;
    sh_s[tid] = (wb[tid] - mean[tid]) * s + beta[tid];
  }
  __syncthreads();

  f32x4 acc[4][4];
  #pragma unroll
  for (int m = 0; m < 4; m++)
    #pragma unroll
    for (int n = 0; n < 4; n++) acc[m][n] = (f32x4)0.0f;

  #pragma unroll
  for (int kk = 0; kk < 4; kk++) {
    short8 af[4], bfr[4];
    #pragma unroll
    for (int m = 0; m < 4; m++)
      af[m] = *reinterpret_cast<const short8*>(
          ww + (size_t)(wave * 64 + m * 16 + lr) * 128 + kk * 32 + lg * 8);
    #pragma unroll
    for (int n = 0; n < 4; n++)
      bfr[n] = *reinterpret_cast<const short8*>(&y_s[n * 16 + lr][kk * 32 + lg * 8]);
    #pragma unroll
    for (int m = 0; m < 4; m++)
      #pragma unroll
      for (int n = 0; n < 4; n++)
        acc[m][n] = MFMA16(af[m], bfr[n], acc[m][n]);
  }

  #pragma unroll
  for (int m = 0; m < 4; m++) {
    #pragma unroll
    for (int n = 0; n < 4; n++) {
      #pragma unroll
      for (int r = 0; r < 4; r++) {
        int co = wave * 64 + m * 16 + lg * 4 + r;
        int q = q0 + n * 16 + lr;
        size_t oidx = ((size_t)b * 256 + co) * 4096 + q;
        float v = acc[m][n][r] * sc_s[co] + sh_s[co];
        out[oidx] = v + x[oidx];
      }
    }
  }
}

// ---------------------------------------------------------------------------
extern "C" void kernel_launch(void* const* d_in, const int* in_sizes, int n_in,
                              void* d_out, int out_size, void* d_ws, size_t ws_size,
                              hipStream_t stream)
{
  const float* x    = (const float*)d_in[0];
  const float* nb   = (const float*)d_in[1];
  const float* g_w  = (const float*)d_in[2];
  const float* g_b  = (const float*)d_in[3];
  const float* th_w = (const float*)d_in[4];
  const float* th_b = (const float*)d_in[5];
  const float* ph_w = (const float*)d_in[6];
  const float* ph_b = (const float*)d_in[7];
  const float* w_w  = (const float*)d_in[8];
  const float* w_b  = (const float*)d_in[9];
  const float* gam  = (const float*)d_in[10];
  const float* bet  = (const float*)d_in[11];
  const float* mu   = (const float*)d_in[12];
  const float* var  = (const float*)d_in[13];
  float* out = (float*)d_out;

  char* ws = (char*)d_ws;
  short* theta_full = (short*)(ws);                        // 8 MB  [b][4096][128]
  short* phi_full   = (short*)(ws + (size_t)(8u << 20));   // 8 MB; reused as pacc0
  short* g_full     = (short*)(ws + (size_t)(16u << 20));  // 8 MB; reused as pacc1
  short* phi_kc     = (short*)(ws + (size_t)(24u << 20));  // 2 MB  [b][1024][128]
  short* g_ck       = (short*)(ws + (size_t)(26u << 20));  // 2 MB  [b][128][1024]
  short* yb         = (short*)(ws + (size_t)(28u << 20));  // 8 MB  [b][4096][128]
  short* wts        = (short*)(ws + (size_t)(36u << 20));  // 256KB: th, ph, g, w
  float* pm         = (float*)(ws + (size_t)(37u << 20));  // 256KB [2][8][4096]
  float* pl         = (float*)(ws + (size_t)(38u << 20));  // 256KB [2][8][4096]
  short* th_wb = wts;
  short* ph_wb = wts + 32768;
  short* g_wb  = wts + 2 * 32768;
  short* w_wb  = wts + 3 * 32768;

  cvt_w<<<dim3(32, 4), 256, 0, stream>>>(th_w, ph_w, g_w, w_w, wts);
  conv_proj<2><<<dim3(64, 8), 256, 0, stream>>>(nb, th_wb, th_b, ph_wb, ph_b,
                                                theta_full, phi_full);
  conv_proj<1><<<dim3(64, 8), 256, 0, stream>>>(x, g_wb, g_b, nullptr, nullptr,
                                                g_full, nullptr);
  pool_phi_k<<<dim3(64, 8), 256, 0, stream>>>(phi_full, phi_kc);
  pool_g_t<<<dim3(32, 8), 256, 0, stream>>>(g_full, g_ck);
  attn_split<<<dim3(32, 8, 2), 256, 0, stream>>>(theta_full, phi_kc, g_ck,
                                                 phi_full, g_full, pm, pl);
  attn_merge<<<dim3(256, 8), 256, 0, stream>>>(phi_full, g_full, pm, pl, yb);
  wconv_bn<<<dim3(64, 8), 256, 0, stream>>>(yb, w_wb, w_b, gam, bet, mu, var, x, out);
}

// Round 6
// 115.616 us; speedup vs baseline: 1.0303x; 1.0303x over previous
//
#include <hip/hip_runtime.h>

typedef __attribute__((ext_vector_type(8))) short short8;
typedef __attribute__((ext_vector_type(4))) short short4v;
typedef __attribute__((ext_vector_type(4))) float f32x4;

__device__ __forceinline__ float bf2f(short s) {
  union { unsigned u; float f; } cv;
  cv.u = ((unsigned)(unsigned short)s) << 16;
  return cv.f;
}
__device__ __forceinline__ short f2bf(float f) {
  union { float f; unsigned u; } cv;
  cv.f = f;
  unsigned r = (cv.u + 0x7fffu + ((cv.u >> 16) & 1u)) >> 16;
  return (short)(unsigned short)r;
}

#define MFMA16(a, b, c) __builtin_amdgcn_mfma_f32_16x16x32_bf16((a), (b), (c), 0, 0, 0)

// ---------------------------------------------------------------------------
// convert fp32 weight matrices -> bf16 workspace. 4 matrices x 32768 elems.
// ---------------------------------------------------------------------------
__global__ __launch_bounds__(256) void cvt_w(
    const float* __restrict__ s0, const float* __restrict__ s1,
    const float* __restrict__ s2, const float* __restrict__ s3,
    short* __restrict__ d)
{
  const float* srcs[4] = {s0, s1, s2, s3};
  const float* s = srcs[blockIdx.y];
  int i = (blockIdx.x * 256 + threadIdx.x) * 4;
  f32x4 v = *reinterpret_cast<const f32x4*>(s + i);
  short4v o;
  #pragma unroll
  for (int j = 0; j < 4; j++) o[j] = f2bf(v[j]);
  *reinterpret_cast<short4v*>(d + (size_t)blockIdx.y * 32768 + i) = o;
}

// ---------------------------------------------------------------------------
// conv1x1: out[b][p][o] = sum_c in[b][c][p] * w[o][c] + bias[o]
// in: fp32 [b][c][4096]; w: bf16 [o][256] (pre-converted); out: bf16 [b][p][o]
// ---------------------------------------------------------------------------
template <int NPROJ>
__global__ __launch_bounds__(256) void conv_proj(
    const float* __restrict__ in,
    const short* __restrict__ w0, const float* __restrict__ bias0,
    const short* __restrict__ w1, const float* __restrict__ bias1,
    short* __restrict__ out0, short* __restrict__ out1)
{
  __shared__ short in_t[64][40];            // [p][c], octet-XOR swizzled
  __shared__ short wt[NPROJ][128][40];      // [o][c], octet-XOR swizzled

  const int b = blockIdx.y;
  const int p0 = blockIdx.x * 64;
  const int tid = threadIdx.x;
  const int wave = tid >> 6, lane = tid & 63;
  const int lr = lane & 15, lg = lane >> 4;

  const short* wsrc[2] = {w0, w1};

  f32x4 acc[NPROJ][8];
  #pragma unroll
  for (int pj = 0; pj < NPROJ; pj++)
    #pragma unroll
    for (int n = 0; n < 8; n++) acc[pj][n] = (f32x4)0.0f;

  for (int kc = 0; kc < 256; kc += 32) {
    __syncthreads();
    {
      int c = tid >> 3;                 // 0..31
      int pg = (tid & 7) * 8;           // pixel group
      const float* src = in + ((size_t)(b * 256 + kc + c)) * 4096 + p0 + pg;
      f32x4 v0 = *reinterpret_cast<const f32x4*>(src);
      f32x4 v1 = *reinterpret_cast<const f32x4*>(src + 4);
      #pragma unroll
      for (int j = 0; j < 8; j++) {
        int p = pg + j;
        float fv = (j < 4) ? v0[j] : v1[j - 4];
        in_t[p][c ^ ((((p >> 3) & 3)) << 3)] = f2bf(fv);
      }
    }
    for (int idx = tid; idx < NPROJ * 128; idx += 256) {
      int pj = idx >> 7, o = idx & 127;
      const short8* src = reinterpret_cast<const short8*>(wsrc[pj] + (size_t)o * 256 + kc);
      int f = (o >> 3) & 3;
      #pragma unroll
      for (int gq = 0; gq < 4; gq++)
        *reinterpret_cast<short8*>(&wt[pj][o][(gq ^ f) * 8]) = src[gq];
    }
    __syncthreads();

    int arow = wave * 16 + lr;
    short8 afrag = *reinterpret_cast<const short8*>(
        &in_t[arow][(lg ^ ((arow >> 3) & 3)) * 8]);
    #pragma unroll
    for (int pj = 0; pj < NPROJ; pj++) {
      #pragma unroll
      for (int n = 0; n < 8; n++) {
        int brow = n * 16 + lr;
        short8 bfrag = *reinterpret_cast<const short8*>(
            &wt[pj][brow][(lg ^ ((brow >> 3) & 3)) * 8]);
        acc[pj][n] = MFMA16(afrag, bfrag, acc[pj][n]);
      }
    }
  }

  const float* bsrc[2] = {bias0, bias1};
  short* osrc[2] = {out0, out1};
  #pragma unroll
  for (int pj = 0; pj < NPROJ; pj++) {
    #pragma unroll
    for (int n = 0; n < 8; n++) {
      int o = n * 16 + lr;
      float bv = bsrc[pj][o];
      #pragma unroll
      for (int r = 0; r < 4; r++) {
        int prow = p0 + wave * 16 + lg * 4 + r;
        osrc[pj][((size_t)b * 4096 + prow) * 128 + o] = f2bf(acc[pj][n][r] + bv);
      }
    }
  }
}

// ---------------------------------------------------------------------------
// maxpool 2x2: src bf16 [b][p=4096][128] -> dst bf16 [b][kp=1024][128]
// ---------------------------------------------------------------------------
__global__ __launch_bounds__(256) void pool_phi_k(const short* __restrict__ src,
                                                  short* __restrict__ dst)
{
  int b = blockIdx.y;
  int kp = blockIdx.x * 16 + (threadIdx.x >> 4);
  int o8 = (threadIdx.x & 15) * 8;
  int ph = kp >> 5, pw = kp & 31;
  size_t base = ((size_t)b * 4096 + ph * 128 + pw * 2) * 128 + o8;
  short8 v0 = *reinterpret_cast<const short8*>(src + base);
  short8 v1 = *reinterpret_cast<const short8*>(src + base + 128);
  short8 v2 = *reinterpret_cast<const short8*>(src + base + 64 * 128);
  short8 v3 = *reinterpret_cast<const short8*>(src + base + 65 * 128);
  short8 o;
  #pragma unroll
  for (int j = 0; j < 8; j++) {
    float m = fmaxf(fmaxf(bf2f(v0[j]), bf2f(v1[j])), fmaxf(bf2f(v2[j]), bf2f(v3[j])));
    o[j] = f2bf(m);
  }
  *reinterpret_cast<short8*>(dst + ((size_t)b * 1024 + kp) * 128 + o8) = o;
}

// ---------------------------------------------------------------------------
// maxpool 2x2 + transpose: src bf16 [b][p=4096][128] -> dst bf16 [b][128][kp=1024]
// ---------------------------------------------------------------------------
__global__ __launch_bounds__(256) void pool_g_t(const short* __restrict__ src,
                                                short* __restrict__ dst)
{
  __shared__ short s[32][136];
  int b = blockIdx.y;
  int kp0 = blockIdx.x * 32;
  int t = threadIdx.x;
  {
    int kpl = t >> 3;
    int o0 = (t & 7) * 16;
    int kp = kp0 + kpl;
    int ph = kp >> 5, pw = kp & 31;
    size_t base = ((size_t)b * 4096 + ph * 128 + pw * 2) * 128;
    #pragma unroll
    for (int h = 0; h < 2; h++) {
      int oo = o0 + h * 8;
      short8 v0 = *reinterpret_cast<const short8*>(src + base + oo);
      short8 v1 = *reinterpret_cast<const short8*>(src + base + 128 + oo);
      short8 v2 = *reinterpret_cast<const short8*>(src + base + 64 * 128 + oo);
      short8 v3 = *reinterpret_cast<const short8*>(src + base + 65 * 128 + oo);
      #pragma unroll
      for (int j = 0; j < 8; j++) {
        float m = fmaxf(fmaxf(bf2f(v0[j]), bf2f(v1[j])), fmaxf(bf2f(v2[j]), bf2f(v3[j])));
        s[kpl][oo + j] = f2bf(m);
      }
    }
  }
  __syncthreads();
  {
    int o = t >> 1;
    int k0 = (t & 1) * 16;
    short8 v0, v1;
    #pragma unroll
    for (int j = 0; j < 8; j++) { v0[j] = s[k0 + j][o]; v1[j] = s[k0 + 8 + j][o]; }
    *reinterpret_cast<short8*>(dst + ((size_t)b * 128 + o) * 1024 + kp0 + k0) = v0;
    *reinterpret_cast<short8*>(dst + ((size_t)b * 128 + o) * 1024 + kp0 + k0 + 8) = v1;
  }
}

// ---------------------------------------------------------------------------
// flash attention v5: split-KV x2, single-buffered LDS (48 KB -> 2 blocks/CU).
// Grid (32 qtiles, 8 b, 2 kv-halves). QBLK=128 (4 waves x 32 q), KVBLK=64.
// Swapped QK^T, defer-rescale THR=10, setprio around MFMA clusters,
// exports unnormalized acc + (m,l); merge fused into wconv_bn.
// ---------------------------------------------------------------------------
__global__ __launch_bounds__(256) void attn_split(
    const short* __restrict__ theta, const short* __restrict__ phi,
    const short* __restrict__ g,
    short* __restrict__ pacc0, short* __restrict__ pacc1,
    float* __restrict__ pm, float* __restrict__ pl)
{
  __shared__ short phi_s[64][128];      // rows 256B = 16 slots, key = kv&15
  __shared__ short g_s[128][64];        // rows 128B = 8 slots,  key = ci&7
  __shared__ short p_s[4][32][64];      // per-wave, rows 128B,  key = q&7

  const int b = blockIdx.y;
  const int q0 = blockIdx.x * 128;
  const int z = blockIdx.z;
  const int tid = threadIdx.x;
  const int wave = tid >> 6, lane = tid & 63;
  const int lr = lane & 15, lg = lane >> 4;

  // theta fragments (32 q rows per wave: two 16-row halves)
  short8 ath[2][4];
  {
    const short* tq = theta + ((size_t)b * 4096 + q0 + wave * 32 + lr) * 128 + lg * 8;
    #pragma unroll
    for (int qh = 0; qh < 2; qh++)
      #pragma unroll
      for (int kk = 0; kk < 4; kk++)
        ath[qh][kk] = *reinterpret_cast<const short8*>(tq + qh * 16 * 128 + kk * 32);
  }

  // staging: thread covers 64B of phi tile and 64B of g tile (linear global)
  const int pr = tid >> 2, pcq = tid & 3;     // phi row 0..63, quarter
  const int gr = tid >> 1, ghq = tid & 1;     // g row 0..127, half
  const short* phi_src = phi + ((size_t)b * 1024 + z * 512 + pr) * 128 + pcq * 32;
  const short* g_src   = g + ((size_t)b * 128 + gr) * 1024 + z * 512 + ghq * 32;

  short8 sphi[4], sg[4];
  #pragma unroll
  for (int j = 0; j < 4; j++) {
    sphi[j] = *reinterpret_cast<const short8*>(phi_src + j * 8);
    sg[j]   = *reinterpret_cast<const short8*>(g_src + j * 8);
  }

  float mrun[2] = {-1e30f, -1e30f}, lpart[2] = {0.0f, 0.0f};
  f32x4 acc[2][8];
  #pragma unroll
  for (int qh = 0; qh < 2; qh++)
    #pragma unroll
    for (int n = 0; n < 8; n++) acc[qh][n] = (f32x4)0.0f;

  char* const phib = (char*)&phi_s[0][0];
  char* const gbse = (char*)&g_s[0][0];
  char* const pbase = (char*)&p_s[wave][0][0];
  const int pkey = (lr & 7) << 4;

  for (int t = 0; t < 8; t++) {
    // write staged tile t (swizzled slots)
    #pragma unroll
    for (int j = 0; j < 4; j++) {
      *reinterpret_cast<short8*>(phib + pr * 256 + (((pcq * 4 + j) ^ (pr & 15)) * 16)) = sphi[j];
      *reinterpret_cast<short8*>(gbse + gr * 128 + (((ghq * 4 + j) ^ (gr & 7)) * 16)) = sg[j];
    }
    __syncthreads();

    // issue loads for tile t+1 (land during compute)
    if (t < 7) {
      const short* ps = phi_src + (t + 1) * 64 * 128;
      const short* gs = g_src + (t + 1) * 64;
      #pragma unroll
      for (int j = 0; j < 4; j++) {
        sphi[j] = *reinterpret_cast<const short8*>(ps + j * 8);
        sg[j]   = *reinterpret_cast<const short8*>(gs + j * 8);
      }
    }

    // QK^T swapped: facc[qh][n] = S^T tile [kv=16n..][q=qh*16..]
    f32x4 facc[2][4];
    #pragma unroll
    for (int qh = 0; qh < 2; qh++)
      #pragma unroll
      for (int n = 0; n < 4; n++) facc[qh][n] = (f32x4)0.0f;
    __builtin_amdgcn_s_setprio(1);
    #pragma unroll
    for (int kk = 0; kk < 4; kk++) {
      #pragma unroll
      for (int n = 0; n < 4; n++) {
        int row = n * 16 + lr;
        short8 pf = *reinterpret_cast<const short8*>(
            phib + row * 256 + (((4 * kk + lg) ^ (row & 15)) * 16));
        facc[0][n] = MFMA16(pf, ath[0][kk], facc[0][n]);
        facc[1][n] = MFMA16(pf, ath[1][kk], facc[1][n]);
      }
    }
    __builtin_amdgcn_s_setprio(0);

    // online softmax with defer-rescale (THR=10): lane owns q = qh*16+lr
    float pmax[2];
    #pragma unroll
    for (int qh = 0; qh < 2; qh++) {
      float m0 = fmaxf(fmaxf(facc[qh][0][0], facc[qh][0][1]), fmaxf(facc[qh][0][2], facc[qh][0][3]));
      float m1 = fmaxf(fmaxf(facc[qh][1][0], facc[qh][1][1]), fmaxf(facc[qh][1][2], facc[qh][1][3]));
      float m2 = fmaxf(fmaxf(facc[qh][2][0], facc[qh][2][1]), fmaxf(facc[qh][2][2], facc[qh][2][3]));
      float m3 = fmaxf(fmaxf(facc[qh][3][0], facc[qh][3][1]), fmaxf(facc[qh][3][2], facc[qh][3][3]));
      float m = fmaxf(fmaxf(m0, m1), fmaxf(m2, m3));
      m = fmaxf(m, __shfl_xor(m, 16));
      m = fmaxf(m, __shfl_xor(m, 32));
      pmax[qh] = m;
    }
    bool need = (pmax[0] - mrun[0] > 10.0f) | (pmax[1] - mrun[1] > 10.0f);
    if (__any(need)) {
      float mn0 = fmaxf(mrun[0], pmax[0]);
      float mn1 = fmaxf(mrun[1], pmax[1]);
      float sc0 = __expf(mrun[0] - mn0);
      float sc1 = __expf(mrun[1] - mn1);
      mrun[0] = mn0; mrun[1] = mn1;
      lpart[0] *= sc0; lpart[1] *= sc1;
      #pragma unroll
      for (int r = 0; r < 4; r++) {
        float s0 = __shfl(sc0, lg * 4 + r);
        float s1 = __shfl(sc1, lg * 4 + r);
        #pragma unroll
        for (int n = 0; n < 8; n++) { acc[0][n][r] *= s0; acc[1][n][r] *= s1; }
      }
    }
    // P = exp(S - m): pack 4 kv values -> one b64 write per (qh, n)
    #pragma unroll
    for (int qh = 0; qh < 2; qh++) {
      #pragma unroll
      for (int n = 0; n < 4; n++) {
        float e0 = __expf(facc[qh][n][0] - mrun[qh]);
        float e1 = __expf(facc[qh][n][1] - mrun[qh]);
        float e2 = __expf(facc[qh][n][2] - mrun[qh]);
        float e3 = __expf(facc[qh][n][3] - mrun[qh]);
        lpart[qh] += (e0 + e1) + (e2 + e3);
        short4v pk;
        pk[0] = f2bf(e0); pk[1] = f2bf(e1); pk[2] = f2bf(e2); pk[3] = f2bf(e3);
        *reinterpret_cast<short4v*>(
            pbase + (qh * 16 + lr) * 128 + ((n * 32 + lg * 8) ^ pkey)) = pk;
      }
    }

    // y^T accumulate: acc[qh][n] += P[qh] . g  (A from p_s, B from g_s)
    __builtin_amdgcn_s_setprio(1);
    #pragma unroll
    for (int kk = 0; kk < 2; kk++) {
      short8 pa0 = *reinterpret_cast<const short8*>(
          pbase + lr * 128 + ((kk * 64 + lg * 16) ^ pkey));
      short8 pa1 = *reinterpret_cast<const short8*>(
          pbase + (16 + lr) * 128 + ((kk * 64 + lg * 16) ^ pkey));
      #pragma unroll
      for (int n = 0; n < 8; n++) {
        int row = n * 16 + lr;
        short8 gf = *reinterpret_cast<const short8*>(
            gbse + row * 128 + (((4 * kk + lg) ^ (row & 7)) * 16));
        acc[0][n] = MFMA16(pa0, gf, acc[0][n]);
        acc[1][n] = MFMA16(pa1, gf, acc[1][n]);
      }
    }
    __builtin_amdgcn_s_setprio(0);
    __syncthreads();   // protect phi_s/g_s before next iteration's writes
  }

  // export (m, l) per q and unnormalized partial acc
  float lsum[2];
  #pragma unroll
  for (int qh = 0; qh < 2; qh++) {
    float s = lpart[qh];
    s += __shfl_xor(s, 16);
    s += __shfl_xor(s, 32);
    lsum[qh] = s;
  }
  if (lane < 16) {
    #pragma unroll
    for (int qh = 0; qh < 2; qh++) {
      int q = q0 + wave * 32 + qh * 16 + lr;
      pm[z * 32768 + b * 4096 + q] = mrun[qh];
      pl[z * 32768 + b * 4096 + q] = lsum[qh];
    }
  }
  short* pacc = z ? pacc1 : pacc0;
  #pragma unroll
  for (int qh = 0; qh < 2; qh++) {
    #pragma unroll
    for (int n = 0; n < 8; n++) {
      #pragma unroll
      for (int r = 0; r < 4; r++) {
        int q = q0 + wave * 32 + qh * 16 + lg * 4 + r;
        pacc[((size_t)b * 4096 + q) * 128 + n * 16 + lr] = f2bf(acc[qh][n][r]);
      }
    }
  }
}

// ---------------------------------------------------------------------------
// fused: merge KV-half partials -> y tile (LDS), then
// wy = w_w . y + bias, BN (eval), + x -> out fp32 [b][256][4096]
// ---------------------------------------------------------------------------
__global__ __launch_bounds__(256) void wconv_bn(
    const short* __restrict__ a0, const short* __restrict__ a1,
    const float* __restrict__ pm, const float* __restrict__ pl,
    const short* __restrict__ ww, const float* __restrict__ wb,
    const float* __restrict__ gamma, const float* __restrict__ beta,
    const float* __restrict__ mean, const float* __restrict__ var,
    const float* __restrict__ x, float* __restrict__ out)
{
  __shared__ short y_s[64][136];
  __shared__ float sc_s[256];
  __shared__ float sh_s[256];

  const int b = blockIdx.y;
  const int q0 = blockIdx.x * 64;
  const int tid = threadIdx.x;
  const int wave = tid >> 6, lane = tid & 63;
  const int lr = lane & 15, lg = lane >> 4;

  {
    int r = tid >> 2, c0 = (tid & 3) * 32;
    int iq = b * 4096 + q0 + r;
    float m0 = pm[iq], m1 = pm[32768 + iq];
    float l0 = pl[iq], l1 = pl[32768 + iq];
    float M = fmaxf(m0, m1);
    float w0 = __expf(m0 - M), w1 = __expf(m1 - M);
    float inv = 1.0f / (w0 * l0 + w1 * l1);
    w0 *= inv; w1 *= inv;
    size_t base = (size_t)iq * 128 + c0;
    #pragma unroll
    for (int j = 0; j < 4; j++) {
      short8 A0 = *reinterpret_cast<const short8*>(a0 + base + j * 8);
      short8 A1 = *reinterpret_cast<const short8*>(a1 + base + j * 8);
      short8 o;
      #pragma unroll
      for (int e = 0; e < 8; e++)
        o[e] = f2bf(w0 * bf2f(A0[e]) + w1 * bf2f(A1[e]));
      *reinterpret_cast<short8*>(&y_s[r][c0 + j * 8]) = o;
    }
    float s = gamma[tid] * rsqrtf(var[tid] + 1e-5f);
    sc_s[tid] = s;
    sh_s[tid] = (wb[tid] - mean[tid]) * s + beta[tid];
  }
  __syncthreads();

  f32x4 acc[4][4];
  #pragma unroll
  for (int m = 0; m < 4; m++)
    #pragma unroll
    for (int n = 0; n < 4; n++) acc[m][n] = (f32x4)0.0f;

  #pragma unroll
  for (int kk = 0; kk < 4; kk++) {
    short8 af[4], bfr[4];
    #pragma unroll
    for (int m = 0; m < 4; m++)
      af[m] = *reinterpret_cast<const short8*>(
          ww + (size_t)(wave * 64 + m * 16 + lr) * 128 + kk * 32 + lg * 8);
    #pragma unroll
    for (int n = 0; n < 4; n++)
      bfr[n] = *reinterpret_cast<const short8*>(&y_s[n * 16 + lr][kk * 32 + lg * 8]);
    #pragma unroll
    for (int m = 0; m < 4; m++)
      #pragma unroll
      for (int n = 0; n < 4; n++)
        acc[m][n] = MFMA16(af[m], bfr[n], acc[m][n]);
  }

  #pragma unroll
  for (int m = 0; m < 4; m++) {
    #pragma unroll
    for (int n = 0; n < 4; n++) {
      #pragma unroll
      for (int r = 0; r < 4; r++) {
        int co = wave * 64 + m * 16 + lg * 4 + r;
        int q = q0 + n * 16 + lr;
        size_t oidx = ((size_t)b * 256 + co) * 4096 + q;
        float v = acc[m][n][r] * sc_s[co] + sh_s[co];
        out[oidx] = v + x[oidx];
      }
    }
  }
}

// ---------------------------------------------------------------------------
extern "C" void kernel_launch(void* const* d_in, const int* in_sizes, int n_in,
                              void* d_out, int out_size, void* d_ws, size_t ws_size,
                              hipStream_t stream)
{
  const float* x    = (const float*)d_in[0];
  const float* nb   = (const float*)d_in[1];
  const float* g_w  = (const float*)d_in[2];
  const float* g_b  = (const float*)d_in[3];
  const float* th_w = (const float*)d_in[4];
  const float* th_b = (const float*)d_in[5];
  const float* ph_w = (const float*)d_in[6];
  const float* ph_b = (const float*)d_in[7];
  const float* w_w  = (const float*)d_in[8];
  const float* w_b  = (const float*)d_in[9];
  const float* gam  = (const float*)d_in[10];
  const float* bet  = (const float*)d_in[11];
  const float* mu   = (const float*)d_in[12];
  const float* var  = (const float*)d_in[13];
  float* out = (float*)d_out;

  char* ws = (char*)d_ws;
  short* theta_full = (short*)(ws);                        // 8 MB  [b][4096][128]
  short* phi_full   = (short*)(ws + (size_t)(8u << 20));   // 8 MB; reused as pacc0
  short* g_full     = (short*)(ws + (size_t)(16u << 20));  // 8 MB; reused as pacc1
  short* phi_kc     = (short*)(ws + (size_t)(24u << 20));  // 2 MB  [b][1024][128]
  short* g_ck       = (short*)(ws + (size_t)(26u << 20));  // 2 MB  [b][128][1024]
  short* wts        = (short*)(ws + (size_t)(36u << 20));  // 256KB: th, ph, g, w
  float* pm         = (float*)(ws + (size_t)(37u << 20));  // 256KB [2][8][4096]
  float* pl         = (float*)(ws + (size_t)(38u << 20));  // 256KB [2][8][4096]
  short* th_wb = wts;
  short* ph_wb = wts + 32768;
  short* g_wb  = wts + 2 * 32768;
  short* w_wb  = wts + 3 * 32768;

  cvt_w<<<dim3(32, 4), 256, 0, stream>>>(th_w, ph_w, g_w, w_w, wts);
  conv_proj<2><<<dim3(64, 8), 256, 0, stream>>>(nb, th_wb, th_b, ph_wb, ph_b,
                                                theta_full, phi_full);
  conv_proj<1><<<dim3(64, 8), 256, 0, stream>>>(x, g_wb, g_b, nullptr, nullptr,
                                                g_full, nullptr);
  pool_phi_k<<<dim3(64, 8), 256, 0, stream>>>(phi_full, phi_kc);
  pool_g_t<<<dim3(32, 8), 256, 0, stream>>>(g_full, g_ck);
  attn_split<<<dim3(32, 8, 2), 256, 0, stream>>>(theta_full, phi_kc, g_ck,
                                                 phi_full, g_full, pm, pl);
  wconv_bn<<<dim3(64, 8), 256, 0, stream>>>(phi_full, g_full, pm, pl,
                                            w_wb, w_b, gam, bet, mu, var, x, out);
}

// Round 7
// 99.655 us; speedup vs baseline: 1.1953x; 1.1602x over previous
//
#include <hip/hip_runtime.h>

typedef __attribute__((ext_vector_type(8))) short short8;
typedef __attribute__((ext_vector_type(4))) short short4v;
typedef __attribute__((ext_vector_type(4))) float f32x4;

__device__ __forceinline__ float bf2f(short s) {
  union { unsigned u; float f; } cv;
  cv.u = ((unsigned)(unsigned short)s) << 16;
  return cv.f;
}
__device__ __forceinline__ short f2bf(float f) {
  union { float f; unsigned u; } cv;
  cv.f = f;
  unsigned r = (cv.u + 0x7fffu + ((cv.u >> 16) & 1u)) >> 16;
  return (short)(unsigned short)r;
}

#define MFMA16(a, b, c) __builtin_amdgcn_mfma_f32_16x16x32_bf16((a), (b), (c), 0, 0, 0)

// ---------------------------------------------------------------------------
// convert fp32 weight matrices -> bf16 workspace. 4 matrices x 32768 elems.
// ---------------------------------------------------------------------------
__global__ __launch_bounds__(256) void cvt_w(
    const float* __restrict__ s0, const float* __restrict__ s1,
    const float* __restrict__ s2, const float* __restrict__ s3,
    short* __restrict__ d)
{
  const float* srcs[4] = {s0, s1, s2, s3};
  const float* s = srcs[blockIdx.y];
  int i = (blockIdx.x * 256 + threadIdx.x) * 4;
  f32x4 v = *reinterpret_cast<const f32x4*>(s + i);
  short4v o;
  #pragma unroll
  for (int j = 0; j < 4; j++) o[j] = f2bf(v[j]);
  *reinterpret_cast<short4v*>(d + (size_t)blockIdx.y * 32768 + i) = o;
}

// ---------------------------------------------------------------------------
// conv1x1: out[b][p][o] = sum_c in[b][c][p] * w[o][c] + bias[o]
// 512 threads, 8 waves x 16 px, 128-px tiles, grid (32,8) = 256 = 1 block/CU.
// ---------------------------------------------------------------------------
template <int NPROJ>
__global__ __launch_bounds__(512) void conv_proj(
    const float* __restrict__ in,
    const short* __restrict__ w0, const float* __restrict__ bias0,
    const short* __restrict__ w1, const float* __restrict__ bias1,
    short* __restrict__ out0, short* __restrict__ out1)
{
  __shared__ short in_t[128][40];           // [p][c], octet-XOR swizzled
  __shared__ short wt[NPROJ][128][40];      // [o][c], octet-XOR swizzled

  const int b = blockIdx.y;
  const int p0 = blockIdx.x * 128;
  const int tid = threadIdx.x;
  const int wave = tid >> 6, lane = tid & 63;
  const int lr = lane & 15, lg = lane >> 4;

  const short* wsrc[2] = {w0, w1};

  f32x4 acc[NPROJ][8];
  #pragma unroll
  for (int pj = 0; pj < NPROJ; pj++)
    #pragma unroll
    for (int n = 0; n < 8; n++) acc[pj][n] = (f32x4)0.0f;

  for (int kc = 0; kc < 256; kc += 32) {
    __syncthreads();
    {
      int c = tid >> 4;                 // 0..31
      int pg = (tid & 15) * 8;          // pixel group 0..120
      const float* src = in + ((size_t)(b * 256 + kc + c)) * 4096 + p0 + pg;
      f32x4 v0 = *reinterpret_cast<const f32x4*>(src);
      f32x4 v1 = *reinterpret_cast<const f32x4*>(src + 4);
      #pragma unroll
      for (int j = 0; j < 8; j++) {
        int p = pg + j;
        float fv = (j < 4) ? v0[j] : v1[j - 4];
        in_t[p][c ^ ((((p >> 3) & 3)) << 3)] = f2bf(fv);
      }
    }
    if (tid < NPROJ * 128) {
      int pj = tid >> 7, o = tid & 127;
      const short8* src = reinterpret_cast<const short8*>(wsrc[pj] + (size_t)o * 256 + kc);
      int f = (o >> 3) & 3;
      #pragma unroll
      for (int gq = 0; gq < 4; gq++)
        *reinterpret_cast<short8*>(&wt[pj][o][(gq ^ f) * 8]) = src[gq];
    }
    __syncthreads();

    int arow = wave * 16 + lr;
    short8 afrag = *reinterpret_cast<const short8*>(
        &in_t[arow][(lg ^ ((arow >> 3) & 3)) * 8]);
    #pragma unroll
    for (int pj = 0; pj < NPROJ; pj++) {
      #pragma unroll
      for (int n = 0; n < 8; n++) {
        int brow = n * 16 + lr;
        short8 bfrag = *reinterpret_cast<const short8*>(
            &wt[pj][brow][(lg ^ ((brow >> 3) & 3)) * 8]);
        acc[pj][n] = MFMA16(afrag, bfrag, acc[pj][n]);
      }
    }
  }

  const float* bsrc[2] = {bias0, bias1};
  short* osrc[2] = {out0, out1};
  #pragma unroll
  for (int pj = 0; pj < NPROJ; pj++) {
    #pragma unroll
    for (int n = 0; n < 8; n++) {
      int o = n * 16 + lr;
      float bv = bsrc[pj][o];
      #pragma unroll
      for (int r = 0; r < 4; r++) {
        int prow = p0 + wave * 16 + lg * 4 + r;
        osrc[pj][((size_t)b * 4096 + prow) * 128 + o] = f2bf(acc[pj][n][r] + bv);
      }
    }
  }
}

// ---------------------------------------------------------------------------
// maxpool 2x2: src bf16 [b][p=4096][128] -> dst bf16 [b][kp=1024][128]
// ---------------------------------------------------------------------------
__global__ __launch_bounds__(256) void pool_phi_k(const short* __restrict__ src,
                                                  short* __restrict__ dst)
{
  int b = blockIdx.y;
  int kp = blockIdx.x * 16 + (threadIdx.x >> 4);
  int o8 = (threadIdx.x & 15) * 8;
  int ph = kp >> 5, pw = kp & 31;
  size_t base = ((size_t)b * 4096 + ph * 128 + pw * 2) * 128 + o8;
  short8 v0 = *reinterpret_cast<const short8*>(src + base);
  short8 v1 = *reinterpret_cast<const short8*>(src + base + 128);
  short8 v2 = *reinterpret_cast<const short8*>(src + base + 64 * 128);
  short8 v3 = *reinterpret_cast<const short8*>(src + base + 65 * 128);
  short8 o;
  #pragma unroll
  for (int j = 0; j < 8; j++) {
    float m = fmaxf(fmaxf(bf2f(v0[j]), bf2f(v1[j])), fmaxf(bf2f(v2[j]), bf2f(v3[j])));
    o[j] = f2bf(m);
  }
  *reinterpret_cast<short8*>(dst + ((size_t)b * 1024 + kp) * 128 + o8) = o;
}

// ---------------------------------------------------------------------------
// maxpool 2x2 + transpose: src bf16 [b][p=4096][128] -> dst bf16 [b][128][kp=1024]
// ---------------------------------------------------------------------------
__global__ __launch_bounds__(256) void pool_g_t(const short* __restrict__ src,
                                                short* __restrict__ dst)
{
  __shared__ short s[32][136];
  int b = blockIdx.y;
  int kp0 = blockIdx.x * 32;
  int t = threadIdx.x;
  {
    int kpl = t >> 3;
    int o0 = (t & 7) * 16;
    int kp = kp0 + kpl;
    int ph = kp >> 5, pw = kp & 31;
    size_t base = ((size_t)b * 4096 + ph * 128 + pw * 2) * 128;
    #pragma unroll
    for (int h = 0; h < 2; h++) {
      int oo = o0 + h * 8;
      short8 v0 = *reinterpret_cast<const short8*>(src + base + oo);
      short8 v1 = *reinterpret_cast<const short8*>(src + base + 128 + oo);
      short8 v2 = *reinterpret_cast<const short8*>(src + base + 64 * 128 + oo);
      short8 v3 = *reinterpret_cast<const short8*>(src + base + 65 * 128 + oo);
      #pragma unroll
      for (int j = 0; j < 8; j++) {
        float m = fmaxf(fmaxf(bf2f(v0[j]), bf2f(v1[j])), fmaxf(bf2f(v2[j]), bf2f(v3[j])));
        s[kpl][oo + j] = f2bf(m);
      }
    }
  }
  __syncthreads();
  {
    int o = t >> 1;
    int k0 = (t & 1) * 16;
    short8 v0, v1;
    #pragma unroll
    for (int j = 0; j < 8; j++) { v0[j] = s[k0 + j][o]; v1[j] = s[k0 + 8 + j][o]; }
    *reinterpret_cast<short8*>(dst + ((size_t)b * 128 + o) * 1024 + kp0 + k0) = v0;
    *reinterpret_cast<short8*>(dst + ((size_t)b * 128 + o) * 1024 + kp0 + k0 + 8) = v1;
  }
}

// ---------------------------------------------------------------------------
// flash attention v6: 512 threads / 8 waves (2 waves/SIMD in-block TLP).
// QBLK=256 (8 waves x 32 q), KVBLK=64, split-KV x2. Grid (16,8,2) = 256.
// Swapped QK^T, defer-rescale THR=10, setprio, swizzled single-buffer LDS.
// ---------------------------------------------------------------------------
__global__ __launch_bounds__(512) void attn_split(
    const short* __restrict__ theta, const short* __restrict__ phi,
    const short* __restrict__ g,
    short* __restrict__ pacc0, short* __restrict__ pacc1,
    float* __restrict__ pm, float* __restrict__ pl)
{
  __shared__ short phi_s[64][128];      // rows 256B = 16 slots, key = kv&15
  __shared__ short g_s[128][64];        // rows 128B = 8 slots,  key = ci&7
  __shared__ short p_s[8][32][64];      // per-wave [q][kv], rows 128B, key = q&7

  const int b = blockIdx.y;
  const int q0 = blockIdx.x * 256;
  const int z = blockIdx.z;
  const int tid = threadIdx.x;
  const int wave = tid >> 6, lane = tid & 63;
  const int lr = lane & 15, lg = lane >> 4;

  // theta fragments (32 q rows per wave: two 16-row halves)
  short8 ath[2][4];
  {
    const short* tq = theta + ((size_t)b * 4096 + q0 + wave * 32 + lr) * 128 + lg * 8;
    #pragma unroll
    for (int qh = 0; qh < 2; qh++)
      #pragma unroll
      for (int kk = 0; kk < 4; kk++)
        ath[qh][kk] = *reinterpret_cast<const short8*>(tq + qh * 16 * 128 + kk * 32);
  }

  // staging: 512 threads; 32B (2 x b128 slots) of phi and of g per thread
  const int pr = tid >> 3, pc2 = (tid & 7) * 2;   // phi row 0..63, slot pair
  const int gr = tid >> 2, gc2 = (tid & 3) * 2;   // g row 0..127, slot pair
  const short* phi_src = phi + ((size_t)b * 1024 + z * 512 + pr) * 128 + pc2 * 8;
  const short* g_src   = g + ((size_t)b * 128 + gr) * 1024 + z * 512 + gc2 * 8;

  short8 sphi[2], sg[2];
  #pragma unroll
  for (int j = 0; j < 2; j++) {
    sphi[j] = *reinterpret_cast<const short8*>(phi_src + j * 8);
    sg[j]   = *reinterpret_cast<const short8*>(g_src + j * 8);
  }

  float mrun[2] = {-1e30f, -1e30f}, lpart[2] = {0.0f, 0.0f};
  f32x4 acc[2][8];
  #pragma unroll
  for (int qh = 0; qh < 2; qh++)
    #pragma unroll
    for (int n = 0; n < 8; n++) acc[qh][n] = (f32x4)0.0f;

  char* const phib = (char*)&phi_s[0][0];
  char* const gbse = (char*)&g_s[0][0];
  char* const pbase = (char*)&p_s[wave][0][0];
  const int pkey = (lr & 7) << 4;

  for (int t = 0; t < 8; t++) {
    // write staged tile t (swizzled slots)
    #pragma unroll
    for (int j = 0; j < 2; j++) {
      *reinterpret_cast<short8*>(phib + pr * 256 + (((pc2 + j) ^ (pr & 15)) * 16)) = sphi[j];
      *reinterpret_cast<short8*>(gbse + gr * 128 + (((gc2 + j) ^ (gr & 7)) * 16)) = sg[j];
    }
    __syncthreads();

    // issue loads for tile t+1 (land during compute)
    if (t < 7) {
      const short* ps = phi_src + (t + 1) * 64 * 128;
      const short* gs = g_src + (t + 1) * 64;
      #pragma unroll
      for (int j = 0; j < 2; j++) {
        sphi[j] = *reinterpret_cast<const short8*>(ps + j * 8);
        sg[j]   = *reinterpret_cast<const short8*>(gs + j * 8);
      }
    }

    // QK^T swapped: facc[qh][n] = S^T tile [kv=16n..][q=qh*16..]
    f32x4 facc[2][4];
    #pragma unroll
    for (int qh = 0; qh < 2; qh++)
      #pragma unroll
      for (int n = 0; n < 4; n++) facc[qh][n] = (f32x4)0.0f;
    __builtin_amdgcn_s_setprio(1);
    #pragma unroll
    for (int kk = 0; kk < 4; kk++) {
      #pragma unroll
      for (int n = 0; n < 4; n++) {
        int row = n * 16 + lr;
        short8 pf = *reinterpret_cast<const short8*>(
            phib + row * 256 + (((4 * kk + lg) ^ (row & 15)) * 16));
        facc[0][n] = MFMA16(pf, ath[0][kk], facc[0][n]);
        facc[1][n] = MFMA16(pf, ath[1][kk], facc[1][n]);
      }
    }
    __builtin_amdgcn_s_setprio(0);

    // online softmax with defer-rescale (THR=10): lane owns q = qh*16+lr
    float pmax[2];
    #pragma unroll
    for (int qh = 0; qh < 2; qh++) {
      float m0 = fmaxf(fmaxf(facc[qh][0][0], facc[qh][0][1]), fmaxf(facc[qh][0][2], facc[qh][0][3]));
      float m1 = fmaxf(fmaxf(facc[qh][1][0], facc[qh][1][1]), fmaxf(facc[qh][1][2], facc[qh][1][3]));
      float m2 = fmaxf(fmaxf(facc[qh][2][0], facc[qh][2][1]), fmaxf(facc[qh][2][2], facc[qh][2][3]));
      float m3 = fmaxf(fmaxf(facc[qh][3][0], facc[qh][3][1]), fmaxf(facc[qh][3][2], facc[qh][3][3]));
      float m = fmaxf(fmaxf(m0, m1), fmaxf(m2, m3));
      m = fmaxf(m, __shfl_xor(m, 16));
      m = fmaxf(m, __shfl_xor(m, 32));
      pmax[qh] = m;
    }
    bool need = (pmax[0] - mrun[0] > 10.0f) | (pmax[1] - mrun[1] > 10.0f);
    if (__any(need)) {
      float mn0 = fmaxf(mrun[0], pmax[0]);
      float mn1 = fmaxf(mrun[1], pmax[1]);
      float sc0 = __expf(mrun[0] - mn0);
      float sc1 = __expf(mrun[1] - mn1);
      mrun[0] = mn0; mrun[1] = mn1;
      lpart[0] *= sc0; lpart[1] *= sc1;
      #pragma unroll
      for (int r = 0; r < 4; r++) {
        float s0 = __shfl(sc0, lg * 4 + r);
        float s1 = __shfl(sc1, lg * 4 + r);
        #pragma unroll
        for (int n = 0; n < 8; n++) { acc[0][n][r] *= s0; acc[1][n][r] *= s1; }
      }
    }
    // P = exp(S - m): pack 4 kv values -> one b64 write per (qh, n)
    #pragma unroll
    for (int qh = 0; qh < 2; qh++) {
      #pragma unroll
      for (int n = 0; n < 4; n++) {
        float e0 = __expf(facc[qh][n][0] - mrun[qh]);
        float e1 = __expf(facc[qh][n][1] - mrun[qh]);
        float e2 = __expf(facc[qh][n][2] - mrun[qh]);
        float e3 = __expf(facc[qh][n][3] - mrun[qh]);
        lpart[qh] += (e0 + e1) + (e2 + e3);
        short4v pk;
        pk[0] = f2bf(e0); pk[1] = f2bf(e1); pk[2] = f2bf(e2); pk[3] = f2bf(e3);
        *reinterpret_cast<short4v*>(
            pbase + (qh * 16 + lr) * 128 + ((n * 32 + lg * 8) ^ pkey)) = pk;
      }
    }

    // y^T accumulate: acc[qh][n] += P[qh] . g  (A from p_s, B from g_s)
    __builtin_amdgcn_s_setprio(1);
    #pragma unroll
    for (int kk = 0; kk < 2; kk++) {
      short8 pa0 = *reinterpret_cast<const short8*>(
          pbase + lr * 128 + ((kk * 64 + lg * 16) ^ pkey));
      short8 pa1 = *reinterpret_cast<const short8*>(
          pbase + (16 + lr) * 128 + ((kk * 64 + lg * 16) ^ pkey));
      #pragma unroll
      for (int n = 0; n < 8; n++) {
        int row = n * 16 + lr;
        short8 gf = *reinterpret_cast<const short8*>(
            gbse + row * 128 + (((4 * kk + lg) ^ (row & 7)) * 16));
        acc[0][n] = MFMA16(pa0, gf, acc[0][n]);
        acc[1][n] = MFMA16(pa1, gf, acc[1][n]);
      }
    }
    __builtin_amdgcn_s_setprio(0);
    __syncthreads();   // protect phi_s/g_s before next iteration's writes
  }

  // export (m, l) per q and unnormalized partial acc
  float lsum[2];
  #pragma unroll
  for (int qh = 0; qh < 2; qh++) {
    float s = lpart[qh];
    s += __shfl_xor(s, 16);
    s += __shfl_xor(s, 32);
    lsum[qh] = s;
  }
  if (lane < 16) {
    #pragma unroll
    for (int qh = 0; qh < 2; qh++) {
      int q = q0 + wave * 32 + qh * 16 + lr;
      pm[z * 32768 + b * 4096 + q] = mrun[qh];
      pl[z * 32768 + b * 4096 + q] = lsum[qh];
    }
  }
  short* pacc = z ? pacc1 : pacc0;
  #pragma unroll
  for (int qh = 0; qh < 2; qh++) {
    #pragma unroll
    for (int n = 0; n < 8; n++) {
      #pragma unroll
      for (int r = 0; r < 4; r++) {
        int q = q0 + wave * 32 + qh * 16 + lg * 4 + r;
        pacc[((size_t)b * 4096 + q) * 128 + n * 16 + lr] = f2bf(acc[qh][n][r]);
      }
    }
  }
}

// ---------------------------------------------------------------------------
// fused: merge KV-half partials -> y tile (LDS), then
// wy = w_w . y + bias, BN (eval), + x -> out fp32 [b][256][4096]
// 512 threads, 8 waves x 32 co, 128-q tiles, grid (32,8) = 256.
// ---------------------------------------------------------------------------
__global__ __launch_bounds__(512) void wconv_bn(
    const short* __restrict__ a0, const short* __restrict__ a1,
    const float* __restrict__ pm, const float* __restrict__ pl,
    const short* __restrict__ ww, const float* __restrict__ wb,
    const float* __restrict__ gamma, const float* __restrict__ beta,
    const float* __restrict__ mean, const float* __restrict__ var,
    const float* __restrict__ x, float* __restrict__ out)
{
  __shared__ short y_s[128][136];
  __shared__ float sc_s[256];
  __shared__ float sh_s[256];

  const int b = blockIdx.y;
  const int q0 = blockIdx.x * 128;
  const int tid = threadIdx.x;
  const int wave = tid >> 6, lane = tid & 63;
  const int lr = lane & 15, lg = lane >> 4;

  {
    int r = tid >> 2, c0 = (tid & 3) * 32;
    int iq = b * 4096 + q0 + r;
    float m0 = pm[iq], m1 = pm[32768 + iq];
    float l0 = pl[iq], l1 = pl[32768 + iq];
    float M = fmaxf(m0, m1);
    float w0 = __expf(m0 - M), w1 = __expf(m1 - M);
    float inv = 1.0f / (w0 * l0 + w1 * l1);
    w0 *= inv; w1 *= inv;
    size_t base = (size_t)iq * 128 + c0;
    #pragma unroll
    for (int j = 0; j < 4; j++) {
      short8 A0 = *reinterpret_cast<const short8*>(a0 + base + j * 8);
      short8 A1 = *reinterpret_cast<const short8*>(a1 + base + j * 8);
      short8 o;
      #pragma unroll
      for (int e = 0; e < 8; e++)
        o[e] = f2bf(w0 * bf2f(A0[e]) + w1 * bf2f(A1[e]));
      *reinterpret_cast<short8*>(&y_s[r][c0 + j * 8]) = o;
    }
    if (tid < 256) {
      float s = gamma[tid] * rsqrtf(var[tid] + 1e-5f);
      sc_s[tid] = s;
      sh_s[tid] = (wb[tid] - mean[tid]) * s + beta[tid];
    }
  }
  __syncthreads();

  f32x4 acc[2][8];
  #pragma unroll
  for (int m = 0; m < 2; m++)
    #pragma unroll
    for (int n = 0; n < 8; n++) acc[m][n] = (f32x4)0.0f;

  #pragma unroll
  for (int kk = 0; kk < 4; kk++) {
    short8 af[2], bfr[8];
    #pragma unroll
    for (int m = 0; m < 2; m++)
      af[m] = *reinterpret_cast<const short8*>(
          ww + (size_t)(wave * 32 + m * 16 + lr) * 128 + kk * 32 + lg * 8);
    #pragma unroll
    for (int n = 0; n < 8; n++)
      bfr[n] = *reinterpret_cast<const short8*>(&y_s[n * 16 + lr][kk * 32 + lg * 8]);
    #pragma unroll
    for (int m = 0; m < 2; m++)
      #pragma unroll
      for (int n = 0; n < 8; n++)
        acc[m][n] = MFMA16(af[m], bfr[n], acc[m][n]);
  }

  #pragma unroll
  for (int m = 0; m < 2; m++) {
    #pragma unroll
    for (int n = 0; n < 8; n++) {
      #pragma unroll
      for (int r = 0; r < 4; r++) {
        int co = wave * 32 + m * 16 + lg * 4 + r;
        int q = q0 + n * 16 + lr;
        size_t oidx = ((size_t)b * 256 + co) * 4096 + q;
        float v = acc[m][n][r] * sc_s[co] + sh_s[co];
        out[oidx] = v + x[oidx];
      }
    }
  }
}

// ---------------------------------------------------------------------------
extern "C" void kernel_launch(void* const* d_in, const int* in_sizes, int n_in,
                              void* d_out, int out_size, void* d_ws, size_t ws_size,
                              hipStream_t stream)
{
  const float* x    = (const float*)d_in[0];
  const float* nb   = (const float*)d_in[1];
  const float* g_w  = (const float*)d_in[2];
  const float* g_b  = (const float*)d_in[3];
  const float* th_w = (const float*)d_in[4];
  const float* th_b = (const float*)d_in[5];
  const float* ph_w = (const float*)d_in[6];
  const float* ph_b = (const float*)d_in[7];
  const float* w_w  = (const float*)d_in[8];
  const float* w_b  = (const float*)d_in[9];
  const float* gam  = (const float*)d_in[10];
  const float* bet  = (const float*)d_in[11];
  const float* mu   = (const float*)d_in[12];
  const float* var  = (const float*)d_in[13];
  float* out = (float*)d_out;

  char* ws = (char*)d_ws;
  short* theta_full = (short*)(ws);                        // 8 MB  [b][4096][128]
  short* phi_full   = (short*)(ws + (size_t)(8u << 20));   // 8 MB; reused as pacc0
  short* g_full     = (short*)(ws + (size_t)(16u << 20));  // 8 MB; reused as pacc1
  short* phi_kc     = (short*)(ws + (size_t)(24u << 20));  // 2 MB  [b][1024][128]
  short* g_ck       = (short*)(ws + (size_t)(26u << 20));  // 2 MB  [b][128][1024]
  short* wts        = (short*)(ws + (size_t)(36u << 20));  // 256KB: th, ph, g, w
  float* pm         = (float*)(ws + (size_t)(37u << 20));  // 256KB [2][8][4096]
  float* pl         = (float*)(ws + (size_t)(38u << 20));  // 256KB [2][8][4096]
  short* th_wb = wts;
  short* ph_wb = wts + 32768;
  short* g_wb  = wts + 2 * 32768;
  short* w_wb  = wts + 3 * 32768;

  cvt_w<<<dim3(32, 4), 256, 0, stream>>>(th_w, ph_w, g_w, w_w, wts);
  conv_proj<2><<<dim3(32, 8), 512, 0, stream>>>(nb, th_wb, th_b, ph_wb, ph_b,
                                                theta_full, phi_full);
  conv_proj<1><<<dim3(32, 8), 512, 0, stream>>>(x, g_wb, g_b, nullptr, nullptr,
                                                g_full, nullptr);
  pool_phi_k<<<dim3(64, 8), 256, 0, stream>>>(phi_full, phi_kc);
  pool_g_t<<<dim3(32, 8), 256, 0, stream>>>(g_full, g_ck);
  attn_split<<<dim3(16, 8, 2), 512, 0, stream>>>(theta_full, phi_kc, g_ck,
                                                 phi_full, g_full, pm, pl);
  wconv_bn<<<dim3(32, 8), 512, 0, stream>>>(phi_full, g_full, pm, pl,
                                            w_wb, w_b, gam, bet, mu, var, x, out);
}

// Round 8
// 91.850 us; speedup vs baseline: 1.2969x; 1.0850x over previous
//
#include <hip/hip_runtime.h>

typedef __attribute__((ext_vector_type(8))) short short8;
typedef __attribute__((ext_vector_type(4))) short short4v;
typedef __attribute__((ext_vector_type(4))) float f32x4;

__device__ __forceinline__ float bf2f(short s) {
  union { unsigned u; float f; } cv;
  cv.u = ((unsigned)(unsigned short)s) << 16;
  return cv.f;
}
__device__ __forceinline__ short f2bf(float f) {
  union { float f; unsigned u; } cv;
  cv.f = f;
  unsigned r = (cv.u + 0x7fffu + ((cv.u >> 16) & 1u)) >> 16;
  return (short)(unsigned short)r;
}

#define MFMA16(a, b, c) __builtin_amdgcn_mfma_f32_16x16x32_bf16((a), (b), (c), 0, 0, 0)

// ---------------------------------------------------------------------------
// convert fp32 weight matrices -> bf16 workspace. 4 matrices x 32768 elems.
// ---------------------------------------------------------------------------
__global__ __launch_bounds__(256) void cvt_w(
    const float* __restrict__ s0, const float* __restrict__ s1,
    const float* __restrict__ s2, const float* __restrict__ s3,
    short* __restrict__ d)
{
  const float* srcs[4] = {s0, s1, s2, s3};
  const float* s = srcs[blockIdx.y];
  int i = (blockIdx.x * 256 + threadIdx.x) * 4;
  f32x4 v = *reinterpret_cast<const f32x4*>(s + i);
  short4v o;
  #pragma unroll
  for (int j = 0; j < 4; j++) o[j] = f2bf(v[j]);
  *reinterpret_cast<short4v*>(d + (size_t)blockIdx.y * 32768 + i) = o;
}

// ---------------------------------------------------------------------------
// conv1x1 (+ optional fused 2x2 maxpool epilogues).
// 512 threads, 8 waves x 16 M-rows, 128-px tiles (= image rows {2r,2r+1}),
// grid (32,8) = 256 = 1 block/CU.
// Pixel<->M-row PERMUTATION puts the 4 pool-mates of pooled col l in one
// lane's f32x4: pix(a) = (a>>2)*2 + (a&1) + ((a>>1)&1)*64.  Pooling = in-reg
// max (exact: RNE round and +bias are monotone / commute with max).
// MODE: 0 = full-res out [b][p][o]; 1 = pooled out [b][kp][o];
//       2 = pooled transposed out [b][o][kp].
// conv_theta_phi: proj0 theta full-res, proj1 phi pooled.
// conv_g: proj0 g pooled-transposed.
// ---------------------------------------------------------------------------
template <int NPROJ, int MODE1>
__global__ __launch_bounds__(512) void conv_proj(
    const float* __restrict__ in,
    const short* __restrict__ w0, const float* __restrict__ bias0,
    const short* __restrict__ w1, const float* __restrict__ bias1,
    short* __restrict__ out0, short* __restrict__ out1)
{
  __shared__ short in_t[128][40];           // [a][c], octet-XOR swizzled
  __shared__ short wt[NPROJ][128][40];      // [o][c], octet-XOR swizzled

  const int b = blockIdx.y;
  const int p0 = blockIdx.x * 128;          // 128 pixels = pooled row blockIdx.x
  const int tid = threadIdx.x;
  const int wave = tid >> 6, lane = tid & 63;
  const int lr = lane & 15, lg = lane >> 4;

  const short* wsrc[2] = {w0, w1};

  f32x4 acc[NPROJ][8];
  #pragma unroll
  for (int pj = 0; pj < NPROJ; pj++)
    #pragma unroll
    for (int n = 0; n < 8; n++) acc[pj][n] = (f32x4)0.0f;

  for (int kc = 0; kc < 256; kc += 32) {
    __syncthreads();
    {
      int c = tid >> 4;                 // 0..31
      int pg = (tid & 15) * 8;          // global pixel group 0..120
      const float* src = in + ((size_t)(b * 256 + kc + c)) * 4096 + p0 + pg;
      f32x4 v0 = *reinterpret_cast<const f32x4*>(src);
      f32x4 v1 = *reinterpret_cast<const f32x4*>(src + 4);
      #pragma unroll
      for (int j = 0; j < 8; j++) {
        int p = pg + j;
        // a = row index such that pix(a) = p
        int a = ((p & 63) >> 1) * 4 + ((p >> 6) << 1) + (p & 1);
        float fv = (j < 4) ? v0[j] : v1[j - 4];
        in_t[a][c ^ ((((a >> 3) & 3)) << 3)] = f2bf(fv);
      }
    }
    if (tid < NPROJ * 128) {
      int pj = tid >> 7, o = tid & 127;
      const short8* src = reinterpret_cast<const short8*>(wsrc[pj] + (size_t)o * 256 + kc);
      int f = (o >> 3) & 3;
      #pragma unroll
      for (int gq = 0; gq < 4; gq++)
        *reinterpret_cast<short8*>(&wt[pj][o][(gq ^ f) * 8]) = src[gq];
    }
    __syncthreads();

    int arow = wave * 16 + lr;
    short8 afrag = *reinterpret_cast<const short8*>(
        &in_t[arow][(lg ^ ((arow >> 3) & 3)) * 8]);
    #pragma unroll
    for (int pj = 0; pj < NPROJ; pj++) {
      #pragma unroll
      for (int n = 0; n < 8; n++) {
        int brow = n * 16 + lr;
        short8 bfrag = *reinterpret_cast<const short8*>(
            &wt[pj][brow][(lg ^ ((brow >> 3) & 3)) * 8]);
        acc[pj][n] = MFMA16(afrag, bfrag, acc[pj][n]);
      }
    }
  }

  const float* bsrc[2] = {bias0, bias1};
  short* osrc[2] = {out0, out1};
  const int kp = blockIdx.x * 32 + wave * 4 + lg;   // pooled position of this lane
  #pragma unroll
  for (int pj = 0; pj < NPROJ; pj++) {
    const int mode = (pj == 0 && NPROJ == 2) ? 0 : MODE1;
    #pragma unroll
    for (int n = 0; n < 8; n++) {
      int o = n * 16 + lr;
      float bv = bsrc[pj][o];
      if (mode == 0) {
        #pragma unroll
        for (int r = 0; r < 4; r++) {
          // pixel = pix(wave*16 + lg*4 + r)
          int pix = (wave * 4 + lg) * 2 + (r & 1) + ((r >> 1) & 1) * 64;
          osrc[pj][((size_t)b * 4096 + p0 + pix) * 128 + o] = f2bf(acc[pj][n][r] + bv);
        }
      } else {
        f32x4 v = acc[pj][n];
        float pv = fmaxf(fmaxf(v[0], v[1]), fmaxf(v[2], v[3])) + bv;
        if (mode == 1)
          osrc[pj][((size_t)b * 1024 + kp) * 128 + o] = f2bf(pv);
        else
          osrc[pj][((size_t)b * 128 + o) * 1024 + kp] = f2bf(pv);
      }
    }
  }
}

// ---------------------------------------------------------------------------
// flash attention v6: 512 threads / 8 waves (2 waves/SIMD in-block TLP).
// QBLK=256 (8 waves x 32 q), KVBLK=64, split-KV x2. Grid (16,8,2) = 256.
// Swapped QK^T, defer-rescale THR=10, setprio, swizzled single-buffer LDS.
// ---------------------------------------------------------------------------
__global__ __launch_bounds__(512) void attn_split(
    const short* __restrict__ theta, const short* __restrict__ phi,
    const short* __restrict__ g,
    short* __restrict__ pacc0, short* __restrict__ pacc1,
    float* __restrict__ pm, float* __restrict__ pl)
{
  __shared__ short phi_s[64][128];      // rows 256B = 16 slots, key = kv&15
  __shared__ short g_s[128][64];        // rows 128B = 8 slots,  key = ci&7
  __shared__ short p_s[8][32][64];      // per-wave [q][kv], rows 128B, key = q&7

  const int b = blockIdx.y;
  const int q0 = blockIdx.x * 256;
  const int z = blockIdx.z;
  const int tid = threadIdx.x;
  const int wave = tid >> 6, lane = tid & 63;
  const int lr = lane & 15, lg = lane >> 4;

  // theta fragments (32 q rows per wave: two 16-row halves)
  short8 ath[2][4];
  {
    const short* tq = theta + ((size_t)b * 4096 + q0 + wave * 32 + lr) * 128 + lg * 8;
    #pragma unroll
    for (int qh = 0; qh < 2; qh++)
      #pragma unroll
      for (int kk = 0; kk < 4; kk++)
        ath[qh][kk] = *reinterpret_cast<const short8*>(tq + qh * 16 * 128 + kk * 32);
  }

  // staging: 512 threads; 32B (2 x b128 slots) of phi and of g per thread
  const int pr = tid >> 3, pc2 = (tid & 7) * 2;   // phi row 0..63, slot pair
  const int gr = tid >> 2, gc2 = (tid & 3) * 2;   // g row 0..127, slot pair
  const short* phi_src = phi + ((size_t)b * 1024 + z * 512 + pr) * 128 + pc2 * 8;
  const short* g_src   = g + ((size_t)b * 128 + gr) * 1024 + z * 512 + gc2 * 8;

  short8 sphi[2], sg[2];
  #pragma unroll
  for (int j = 0; j < 2; j++) {
    sphi[j] = *reinterpret_cast<const short8*>(phi_src + j * 8);
    sg[j]   = *reinterpret_cast<const short8*>(g_src + j * 8);
  }

  float mrun[2] = {-1e30f, -1e30f}, lpart[2] = {0.0f, 0.0f};
  f32x4 acc[2][8];
  #pragma unroll
  for (int qh = 0; qh < 2; qh++)
    #pragma unroll
    for (int n = 0; n < 8; n++) acc[qh][n] = (f32x4)0.0f;

  char* const phib = (char*)&phi_s[0][0];
  char* const gbse = (char*)&g_s[0][0];
  char* const pbase = (char*)&p_s[wave][0][0];
  const int pkey = (lr & 7) << 4;

  for (int t = 0; t < 8; t++) {
    // write staged tile t (swizzled slots)
    #pragma unroll
    for (int j = 0; j < 2; j++) {
      *reinterpret_cast<short8*>(phib + pr * 256 + (((pc2 + j) ^ (pr & 15)) * 16)) = sphi[j];
      *reinterpret_cast<short8*>(gbse + gr * 128 + (((gc2 + j) ^ (gr & 7)) * 16)) = sg[j];
    }
    __syncthreads();

    // issue loads for tile t+1 (land during compute)
    if (t < 7) {
      const short* ps = phi_src + (t + 1) * 64 * 128;
      const short* gs = g_src + (t + 1) * 64;
      #pragma unroll
      for (int j = 0; j < 2; j++) {
        sphi[j] = *reinterpret_cast<const short8*>(ps + j * 8);
        sg[j]   = *reinterpret_cast<const short8*>(gs + j * 8);
      }
    }

    // QK^T swapped: facc[qh][n] = S^T tile [kv=16n..][q=qh*16..]
    f32x4 facc[2][4];
    #pragma unroll
    for (int qh = 0; qh < 2; qh++)
      #pragma unroll
      for (int n = 0; n < 4; n++) facc[qh][n] = (f32x4)0.0f;
    __builtin_amdgcn_s_setprio(1);
    #pragma unroll
    for (int kk = 0; kk < 4; kk++) {
      #pragma unroll
      for (int n = 0; n < 4; n++) {
        int row = n * 16 + lr;
        short8 pf = *reinterpret_cast<const short8*>(
            phib + row * 256 + (((4 * kk + lg) ^ (row & 15)) * 16));
        facc[0][n] = MFMA16(pf, ath[0][kk], facc[0][n]);
        facc[1][n] = MFMA16(pf, ath[1][kk], facc[1][n]);
      }
    }
    __builtin_amdgcn_s_setprio(0);

    // online softmax with defer-rescale (THR=10): lane owns q = qh*16+lr
    float pmax[2];
    #pragma unroll
    for (int qh = 0; qh < 2; qh++) {
      float m0 = fmaxf(fmaxf(facc[qh][0][0], facc[qh][0][1]), fmaxf(facc[qh][0][2], facc[qh][0][3]));
      float m1 = fmaxf(fmaxf(facc[qh][1][0], facc[qh][1][1]), fmaxf(facc[qh][1][2], facc[qh][1][3]));
      float m2 = fmaxf(fmaxf(facc[qh][2][0], facc[qh][2][1]), fmaxf(facc[qh][2][2], facc[qh][2][3]));
      float m3 = fmaxf(fmaxf(facc[qh][3][0], facc[qh][3][1]), fmaxf(facc[qh][3][2], facc[qh][3][3]));
      float m = fmaxf(fmaxf(m0, m1), fmaxf(m2, m3));
      m = fmaxf(m, __shfl_xor(m, 16));
      m = fmaxf(m, __shfl_xor(m, 32));
      pmax[qh] = m;
    }
    bool need = (pmax[0] - mrun[0] > 10.0f) | (pmax[1] - mrun[1] > 10.0f);
    if (__any(need)) {
      float mn0 = fmaxf(mrun[0], pmax[0]);
      float mn1 = fmaxf(mrun[1], pmax[1]);
      float sc0 = __expf(mrun[0] - mn0);
      float sc1 = __expf(mrun[1] - mn1);
      mrun[0] = mn0; mrun[1] = mn1;
      lpart[0] *= sc0; lpart[1] *= sc1;
      #pragma unroll
      for (int r = 0; r < 4; r++) {
        float s0 = __shfl(sc0, lg * 4 + r);
        float s1 = __shfl(sc1, lg * 4 + r);
        #pragma unroll
        for (int n = 0; n < 8; n++) { acc[0][n][r] *= s0; acc[1][n][r] *= s1; }
      }
    }
    // P = exp(S - m): pack 4 kv values -> one b64 write per (qh, n)
    #pragma unroll
    for (int qh = 0; qh < 2; qh++) {
      #pragma unroll
      for (int n = 0; n < 4; n++) {
        float e0 = __expf(facc[qh][n][0] - mrun[qh]);
        float e1 = __expf(facc[qh][n][1] - mrun[qh]);
        float e2 = __expf(facc[qh][n][2] - mrun[qh]);
        float e3 = __expf(facc[qh][n][3] - mrun[qh]);
        lpart[qh] += (e0 + e1) + (e2 + e3);
        short4v pk;
        pk[0] = f2bf(e0); pk[1] = f2bf(e1); pk[2] = f2bf(e2); pk[3] = f2bf(e3);
        *reinterpret_cast<short4v*>(
            pbase + (qh * 16 + lr) * 128 + ((n * 32 + lg * 8) ^ pkey)) = pk;
      }
    }

    // y^T accumulate: acc[qh][n] += P[qh] . g  (A from p_s, B from g_s)
    __builtin_amdgcn_s_setprio(1);
    #pragma unroll
    for (int kk = 0; kk < 2; kk++) {
      short8 pa0 = *reinterpret_cast<const short8*>(
          pbase + lr * 128 + ((kk * 64 + lg * 16) ^ pkey));
      short8 pa1 = *reinterpret_cast<const short8*>(
          pbase + (16 + lr) * 128 + ((kk * 64 + lg * 16) ^ pkey));
      #pragma unroll
      for (int n = 0; n < 8; n++) {
        int row = n * 16 + lr;
        short8 gf = *reinterpret_cast<const short8*>(
            gbse + row * 128 + (((4 * kk + lg) ^ (row & 7)) * 16));
        acc[0][n] = MFMA16(pa0, gf, acc[0][n]);
        acc[1][n] = MFMA16(pa1, gf, acc[1][n]);
      }
    }
    __builtin_amdgcn_s_setprio(0);
    __syncthreads();   // protect phi_s/g_s before next iteration's writes
  }

  // export (m, l) per q and unnormalized partial acc
  float lsum[2];
  #pragma unroll
  for (int qh = 0; qh < 2; qh++) {
    float s = lpart[qh];
    s += __shfl_xor(s, 16);
    s += __shfl_xor(s, 32);
    lsum[qh] = s;
  }
  if (lane < 16) {
    #pragma unroll
    for (int qh = 0; qh < 2; qh++) {
      int q = q0 + wave * 32 + qh * 16 + lr;
      pm[z * 32768 + b * 4096 + q] = mrun[qh];
      pl[z * 32768 + b * 4096 + q] = lsum[qh];
    }
  }
  short* pacc = z ? pacc1 : pacc0;
  #pragma unroll
  for (int qh = 0; qh < 2; qh++) {
    #pragma unroll
    for (int n = 0; n < 8; n++) {
      #pragma unroll
      for (int r = 0; r < 4; r++) {
        int q = q0 + wave * 32 + qh * 16 + lg * 4 + r;
        pacc[((size_t)b * 4096 + q) * 128 + n * 16 + lr] = f2bf(acc[qh][n][r]);
      }
    }
  }
}

// ---------------------------------------------------------------------------
// fused: merge KV-half partials -> y tile (LDS), then
// wy = w_w . y + bias, BN (eval), + x -> out fp32 [b][256][4096]
// 512 threads, 8 waves x 32 co, 128-q tiles, grid (32,8) = 256.
// ---------------------------------------------------------------------------
__global__ __launch_bounds__(512) void wconv_bn(
    const short* __restrict__ a0, const short* __restrict__ a1,
    const float* __restrict__ pm, const float* __restrict__ pl,
    const short* __restrict__ ww, const float* __restrict__ wb,
    const float* __restrict__ gamma, const float* __restrict__ beta,
    const float* __restrict__ mean, const float* __restrict__ var,
    const float* __restrict__ x, float* __restrict__ out)
{
  __shared__ short y_s[128][136];
  __shared__ float sc_s[256];
  __shared__ float sh_s[256];

  const int b = blockIdx.y;
  const int q0 = blockIdx.x * 128;
  const int tid = threadIdx.x;
  const int wave = tid >> 6, lane = tid & 63;
  const int lr = lane & 15, lg = lane >> 4;

  {
    int r = tid >> 2, c0 = (tid & 3) * 32;
    int iq = b * 4096 + q0 + r;
    float m0 = pm[iq], m1 = pm[32768 + iq];
    float l0 = pl[iq], l1 = pl[32768 + iq];
    float M = fmaxf(m0, m1);
    float w0 = __expf(m0 - M), w1 = __expf(m1 - M);
    float inv = 1.0f / (w0 * l0 + w1 * l1);
    w0 *= inv; w1 *= inv;
    size_t base = (size_t)iq * 128 + c0;
    #pragma unroll
    for (int j = 0; j < 4; j++) {
      short8 A0 = *reinterpret_cast<const short8*>(a0 + base + j * 8);
      short8 A1 = *reinterpret_cast<const short8*>(a1 + base + j * 8);
      short8 o;
      #pragma unroll
      for (int e = 0; e < 8; e++)
        o[e] = f2bf(w0 * bf2f(A0[e]) + w1 * bf2f(A1[e]));
      *reinterpret_cast<short8*>(&y_s[r][c0 + j * 8]) = o;
    }
    if (tid < 256) {
      float s = gamma[tid] * rsqrtf(var[tid] + 1e-5f);
      sc_s[tid] = s;
      sh_s[tid] = (wb[tid] - mean[tid]) * s + beta[tid];
    }
  }
  __syncthreads();

  f32x4 acc[2][8];
  #pragma unroll
  for (int m = 0; m < 2; m++)
    #pragma unroll
    for (int n = 0; n < 8; n++) acc[m][n] = (f32x4)0.0f;

  #pragma unroll
  for (int kk = 0; kk < 4; kk++) {
    short8 af[2], bfr[8];
    #pragma unroll
    for (int m = 0; m < 2; m++)
      af[m] = *reinterpret_cast<const short8*>(
          ww + (size_t)(wave * 32 + m * 16 + lr) * 128 + kk * 32 + lg * 8);
    #pragma unroll
    for (int n = 0; n < 8; n++)
      bfr[n] = *reinterpret_cast<const short8*>(&y_s[n * 16 + lr][kk * 32 + lg * 8]);
    #pragma unroll
    for (int m = 0; m < 2; m++)
      #pragma unroll
      for (int n = 0; n < 8; n++)
        acc[m][n] = MFMA16(af[m], bfr[n], acc[m][n]);
  }

  #pragma unroll
  for (int m = 0; m < 2; m++) {
    #pragma unroll
    for (int n = 0; n < 8; n++) {
      #pragma unroll
      for (int r = 0; r < 4; r++) {
        int co = wave * 32 + m * 16 + lg * 4 + r;
        int q = q0 + n * 16 + lr;
        size_t oidx = ((size_t)b * 256 + co) * 4096 + q;
        float v = acc[m][n][r] * sc_s[co] + sh_s[co];
        out[oidx] = v + x[oidx];
      }
    }
  }
}

// ---------------------------------------------------------------------------
extern "C" void kernel_launch(void* const* d_in, const int* in_sizes, int n_in,
                              void* d_out, int out_size, void* d_ws, size_t ws_size,
                              hipStream_t stream)
{
  const float* x    = (const float*)d_in[0];
  const float* nb   = (const float*)d_in[1];
  const float* g_w  = (const float*)d_in[2];
  const float* g_b  = (const float*)d_in[3];
  const float* th_w = (const float*)d_in[4];
  const float* th_b = (const float*)d_in[5];
  const float* ph_w = (const float*)d_in[6];
  const float* ph_b = (const float*)d_in[7];
  const float* w_w  = (const float*)d_in[8];
  const float* w_b  = (const float*)d_in[9];
  const float* gam  = (const float*)d_in[10];
  const float* bet  = (const float*)d_in[11];
  const float* mu   = (const float*)d_in[12];
  const float* var  = (const float*)d_in[13];
  float* out = (float*)d_out;

  char* ws = (char*)d_ws;
  short* theta_full = (short*)(ws);                        // 8 MB  [b][4096][128]
  short* pacc0      = (short*)(ws + (size_t)(8u << 20));   // 8 MB  [b][4096][128]
  short* pacc1      = (short*)(ws + (size_t)(16u << 20));  // 8 MB  [b][4096][128]
  short* phi_kc     = (short*)(ws + (size_t)(24u << 20));  // 2 MB  [b][1024][128]
  short* g_ck       = (short*)(ws + (size_t)(26u << 20));  // 2 MB  [b][128][1024]
  short* wts        = (short*)(ws + (size_t)(36u << 20));  // 256KB: th, ph, g, w
  float* pm         = (float*)(ws + (size_t)(37u << 20));  // 256KB [2][8][4096]
  float* pl         = (float*)(ws + (size_t)(38u << 20));  // 256KB [2][8][4096]
  short* th_wb = wts;
  short* ph_wb = wts + 32768;
  short* g_wb  = wts + 2 * 32768;
  short* w_wb  = wts + 3 * 32768;

  cvt_w<<<dim3(32, 4), 256, 0, stream>>>(th_w, ph_w, g_w, w_w, wts);
  // theta (full-res) + phi (fused-pooled) from neighborFeat
  conv_proj<2, 1><<<dim3(32, 8), 512, 0, stream>>>(nb, th_wb, th_b, ph_wb, ph_b,
                                                   theta_full, phi_kc);
  // g (fused-pooled, transposed) from x
  conv_proj<1, 2><<<dim3(32, 8), 512, 0, stream>>>(x, g_wb, g_b, nullptr, nullptr,
                                                   g_ck, nullptr);
  attn_split<<<dim3(16, 8, 2), 512, 0, stream>>>(theta_full, phi_kc, g_ck,
                                                 pacc0, pacc1, pm, pl);
  wconv_bn<<<dim3(32, 8), 512, 0, stream>>>(pacc0, pacc1, pm, pl,
                                            w_wb, w_b, gam, bet, mu, var, x, out);
}

// Round 9
// 89.353 us; speedup vs baseline: 1.3331x; 1.0279x over previous
//
#include <hip/hip_runtime.h>

typedef __attribute__((ext_vector_type(8))) short short8;
typedef __attribute__((ext_vector_type(4))) short short4v;
typedef __attribute__((ext_vector_type(4))) float f32x4;
typedef __attribute__((ext_vector_type(16))) float f32x16;
typedef __attribute__((ext_vector_type(4))) unsigned u32x4;

__device__ __forceinline__ float bf2f(short s) {
  union { unsigned u; float f; } cv;
  cv.u = ((unsigned)(unsigned short)s) << 16;
  return cv.f;
}
__device__ __forceinline__ short f2bf(float f) {
  union { float f; unsigned u; } cv;
  cv.f = f;
  unsigned r = (cv.u + 0x7fffu + ((cv.u >> 16) & 1u)) >> 16;
  return (short)(unsigned short)r;
}
__device__ __forceinline__ unsigned pk2(float a, float b) {
  return (unsigned)(unsigned short)f2bf(a) | ((unsigned)(unsigned short)f2bf(b) << 16);
}

#define MFMA16(a, b, c) __builtin_amdgcn_mfma_f32_16x16x32_bf16((a), (b), (c), 0, 0, 0)
#define MFMA32(a, b, c) __builtin_amdgcn_mfma_f32_32x32x16_bf16((a), (b), (c), 0, 0, 0)

// ---------------------------------------------------------------------------
// convert fp32 weight matrices -> bf16 workspace. 4 matrices x 32768 elems.
// ---------------------------------------------------------------------------
__global__ __launch_bounds__(256) void cvt_w(
    const float* __restrict__ s0, const float* __restrict__ s1,
    const float* __restrict__ s2, const float* __restrict__ s3,
    short* __restrict__ d)
{
  const float* srcs[4] = {s0, s1, s2, s3};
  const float* s = srcs[blockIdx.y];
  int i = (blockIdx.x * 256 + threadIdx.x) * 4;
  f32x4 v = *reinterpret_cast<const f32x4*>(s + i);
  short4v o;
  #pragma unroll
  for (int j = 0; j < 4; j++) o[j] = f2bf(v[j]);
  *reinterpret_cast<short4v*>(d + (size_t)blockIdx.y * 32768 + i) = o;
}

// ---------------------------------------------------------------------------
// conv1x1 (+ optional fused 2x2 maxpool epilogues).  See R8 notes: pixel<->M
// permutation puts a pooled cell's 4 pixels in one lane's f32x4 (exact).
// MODE: 0 full-res [b][p][o]; 1 pooled [b][kp][o]; 2 pooled-T [b][o][kp].
// ---------------------------------------------------------------------------
template <int NPROJ, int MODE1>
__global__ __launch_bounds__(512) void conv_proj(
    const float* __restrict__ in,
    const short* __restrict__ w0, const float* __restrict__ bias0,
    const short* __restrict__ w1, const float* __restrict__ bias1,
    short* __restrict__ out0, short* __restrict__ out1)
{
  __shared__ short in_t[128][40];           // [a][c], octet-XOR swizzled
  __shared__ short wt[NPROJ][128][40];      // [o][c], octet-XOR swizzled

  const int b = blockIdx.y;
  const int p0 = blockIdx.x * 128;
  const int tid = threadIdx.x;
  const int wave = tid >> 6, lane = tid & 63;
  const int lr = lane & 15, lg = lane >> 4;

  const short* wsrc[2] = {w0, w1};

  f32x4 acc[NPROJ][8];
  #pragma unroll
  for (int pj = 0; pj < NPROJ; pj++)
    #pragma unroll
    for (int n = 0; n < 8; n++) acc[pj][n] = (f32x4)0.0f;

  for (int kc = 0; kc < 256; kc += 32) {
    __syncthreads();
    {
      int c = tid >> 4;                 // 0..31
      int pg = (tid & 15) * 8;          // global pixel group 0..120
      const float* src = in + ((size_t)(b * 256 + kc + c)) * 4096 + p0 + pg;
      f32x4 v0 = *reinterpret_cast<const f32x4*>(src);
      f32x4 v1 = *reinterpret_cast<const f32x4*>(src + 4);
      #pragma unroll
      for (int j = 0; j < 8; j++) {
        int p = pg + j;
        int a = ((p & 63) >> 1) * 4 + ((p >> 6) << 1) + (p & 1);
        float fv = (j < 4) ? v0[j] : v1[j - 4];
        in_t[a][c ^ ((((a >> 3) & 3)) << 3)] = f2bf(fv);
      }
    }
    if (tid < NPROJ * 128) {
      int pj = tid >> 7, o = tid & 127;
      const short8* src = reinterpret_cast<const short8*>(wsrc[pj] + (size_t)o * 256 + kc);
      int f = (o >> 3) & 3;
      #pragma unroll
      for (int gq = 0; gq < 4; gq++)
        *reinterpret_cast<short8*>(&wt[pj][o][(gq ^ f) * 8]) = src[gq];
    }
    __syncthreads();

    int arow = wave * 16 + lr;
    short8 afrag = *reinterpret_cast<const short8*>(
        &in_t[arow][(lg ^ ((arow >> 3) & 3)) * 8]);
    #pragma unroll
    for (int pj = 0; pj < NPROJ; pj++) {
      #pragma unroll
      for (int n = 0; n < 8; n++) {
        int brow = n * 16 + lr;
        short8 bfrag = *reinterpret_cast<const short8*>(
            &wt[pj][brow][(lg ^ ((brow >> 3) & 3)) * 8]);
        acc[pj][n] = MFMA16(afrag, bfrag, acc[pj][n]);
      }
    }
  }

  const float* bsrc[2] = {bias0, bias1};
  short* osrc[2] = {out0, out1};
  const int kp = blockIdx.x * 32 + wave * 4 + lg;
  #pragma unroll
  for (int pj = 0; pj < NPROJ; pj++) {
    const int mode = (pj == 0 && NPROJ == 2) ? 0 : MODE1;
    #pragma unroll
    for (int n = 0; n < 8; n++) {
      int o = n * 16 + lr;
      float bv = bsrc[pj][o];
      if (mode == 0) {
        #pragma unroll
        for (int r = 0; r < 4; r++) {
          int pix = (wave * 4 + lg) * 2 + (r & 1) + ((r >> 1) & 1) * 64;
          osrc[pj][((size_t)b * 4096 + p0 + pix) * 128 + o] = f2bf(acc[pj][n][r] + bv);
        }
      } else {
        f32x4 v = acc[pj][n];
        float pv = fmaxf(fmaxf(v[0], v[1]), fmaxf(v[2], v[3])) + bv;
        if (mode == 1)
          osrc[pj][((size_t)b * 1024 + kp) * 128 + o] = f2bf(pv);
        else
          osrc[pj][((size_t)b * 128 + o) * 1024 + kp] = f2bf(pv);
      }
    }
  }
}

// ---------------------------------------------------------------------------
// flash attention v7: 32x32 MFMA, in-register P (shfl_xor32 exchange), no p_s,
// double-buffered phi/g (64KB), 1 barrier/iter.  512 thr / 8 waves x 32 q.
// Split-KV x2, grid (16,8,2)=256.  Swapped QK^T: facc cols = q = lane&31.
// C/D layout (m74/m101): col=lane&31, row=(reg&3)+8*(reg>>2)+4*(lane>>5).
// ---------------------------------------------------------------------------
__global__ __launch_bounds__(512) void attn_split(
    const short* __restrict__ theta, const short* __restrict__ phi,
    const short* __restrict__ g,
    short* __restrict__ pacc0, short* __restrict__ pacc1,
    float* __restrict__ pm, float* __restrict__ pl)
{
  __shared__ short phi_s[2][64][128];   // [buf][kv][ci], rows 256B, 16-slot XOR
  __shared__ short g_s[2][128][64];     // [buf][ci][kv], rows 128B, 8-slot XOR

  const int b = blockIdx.y, z = blockIdx.z;
  const int q0 = blockIdx.x * 256;
  const int tid = threadIdx.x;
  const int wave = tid >> 6, lane = tid & 63;
  const int l31 = lane & 31, hi = lane >> 5;

  // theta B-fragments: lane holds theta[q = l31][k = s*16 + hi*8 + j]
  short8 ath[8];
  {
    const short* tq = theta + ((size_t)b * 4096 + q0 + wave * 32 + l31) * 128 + hi * 8;
    #pragma unroll
    for (int s = 0; s < 8; s++)
      ath[s] = *reinterpret_cast<const short8*>(tq + s * 16);
  }

  // staging: 512 threads, 32B of phi and of g per thread
  const int pr = tid >> 3, pc2 = (tid & 7) * 2;
  const int gr = tid >> 2, gc2 = (tid & 3) * 2;
  const short* phi_src = phi + ((size_t)b * 1024 + z * 512 + pr) * 128 + pc2 * 8;
  const short* g_src   = g + ((size_t)b * 128 + gr) * 1024 + z * 512 + gc2 * 8;

  short8 sphi[2], sg[2];
  #pragma unroll
  for (int j = 0; j < 2; j++) {
    sphi[j] = *reinterpret_cast<const short8*>(phi_src + j * 8);
    sg[j]   = *reinterpret_cast<const short8*>(g_src + j * 8);
  }

  float mrun = -1e30f, lpart = 0.0f;
  f32x16 acc[4];
  #pragma unroll
  for (int n = 0; n < 4; n++) acc[n] = (f32x16)0.0f;

  // prologue: write tile 0 into buf 0
  {
    char* pb = (char*)&phi_s[0][0][0];
    char* gb = (char*)&g_s[0][0][0];
    #pragma unroll
    for (int j = 0; j < 2; j++) {
      *reinterpret_cast<short8*>(pb + pr * 256 + (((pc2 + j) ^ (pr & 15)) * 16)) = sphi[j];
      *reinterpret_cast<short8*>(gb + gr * 128 + (((gc2 + j) ^ (gr & 7)) * 16)) = sg[j];
    }
  }

  for (int t = 0; t < 8; t++) {
    __syncthreads();   // buf[t&1] ready; all waves past iter t-1 reads
    char* pb = (char*)&phi_s[t & 1][0][0];
    char* gb = (char*)&g_s[t & 1][0][0];

    // issue next-tile loads early (land under compute)
    if (t < 7) {
      const short* ps = phi_src + (t + 1) * 64 * 128;
      const short* gs = g_src + (t + 1) * 64;
      #pragma unroll
      for (int j = 0; j < 2; j++) {
        sphi[j] = *reinterpret_cast<const short8*>(ps + j * 8);
        sg[j]   = *reinterpret_cast<const short8*>(gs + j * 8);
      }
    }

    // QK^T: facc[kt] = S^T 32x32 (rows kv = kt*32.., cols q)
    f32x16 facc0 = (f32x16)0.0f, facc1 = (f32x16)0.0f;
    __builtin_amdgcn_s_setprio(1);
    #pragma unroll
    for (int s = 0; s < 8; s++) {
      int slot = (s << 1) | hi;
      short8 pf0 = *reinterpret_cast<const short8*>(
          pb + l31 * 256 + ((slot ^ (l31 & 15)) * 16));
      short8 pf1 = *reinterpret_cast<const short8*>(
          pb + (32 + l31) * 256 + ((slot ^ (l31 & 15)) * 16));
      facc0 = MFMA32(pf0, ath[s], facc0);
      facc1 = MFMA32(pf1, ath[s], facc1);
    }
    __builtin_amdgcn_s_setprio(0);

    // online softmax (lane owns q = l31; one cross-half swap for full row)
    float m = facc0[0];
    #pragma unroll
    for (int r = 1; r < 16; r++) m = fmaxf(m, facc0[r]);
    #pragma unroll
    for (int r = 0; r < 16; r++) m = fmaxf(m, facc1[r]);
    m = fmaxf(m, __shfl_xor(m, 32));
    if (__any(m - mrun > 10.0f)) {
      float mn = fmaxf(mrun, m);
      float sc = __expf(mrun - mn);
      mrun = mn;
      lpart *= sc;
      #pragma unroll
      for (int reg = 0; reg < 16; reg++) {
        int qr = (reg & 3) + 8 * (reg >> 2) + 4 * hi;
        float sr = __shfl(sc, qr);
        #pragma unroll
        for (int n = 0; n < 4; n++) acc[n][reg] *= sr;
      }
    }
    // P = exp(S - m) in place, per-lane partial row sum
    float ls = 0.0f;
    #pragma unroll
    for (int r = 0; r < 16; r++) { facc0[r] = __expf(facc0[r] - mrun); ls += facc0[r]; }
    #pragma unroll
    for (int r = 0; r < 16; r++) { facc1[r] = __expf(facc1[r] - mrun); ls += facc1[r]; }
    lpart += ls;

    // PV: per K-slice s (16 kv), A-frag built in-register:
    // own 4 regs + partner(lane^32) 4 regs; hi selects which j-half is own.
    __builtin_amdgcn_s_setprio(1);
    #pragma unroll
    for (int s = 0; s < 4; s++) {
      const int base = (s & 1) * 8;
      float p0, p1, p2, p3, p4, p5, p6, p7;
      if (s < 2) {
        p0 = facc0[base + 0]; p1 = facc0[base + 1]; p2 = facc0[base + 2]; p3 = facc0[base + 3];
        p4 = facc0[base + 4]; p5 = facc0[base + 5]; p6 = facc0[base + 6]; p7 = facc0[base + 7];
      } else {
        p0 = facc1[base + 0]; p1 = facc1[base + 1]; p2 = facc1[base + 2]; p3 = facc1[base + 3];
        p4 = facc1[base + 4]; p5 = facc1[base + 5]; p6 = facc1[base + 6]; p7 = facc1[base + 7];
      }
      unsigned P0w0 = pk2(p0, p1), P0w1 = pk2(p2, p3);
      unsigned P1w0 = pk2(p4, p5), P1w1 = pk2(p6, p7);
      unsigned x0 = (unsigned)__shfl_xor((int)P0w0, 32);
      unsigned x1 = (unsigned)__shfl_xor((int)P0w1, 32);
      unsigned y0 = (unsigned)__shfl_xor((int)P1w0, 32);
      unsigned y1 = (unsigned)__shfl_xor((int)P1w1, 32);
      union { u32x4 u; short8 s8; } pf;
      pf.u[0] = hi ? y0 : P0w0;
      pf.u[1] = hi ? y1 : P0w1;
      pf.u[2] = hi ? P1w0 : x0;
      pf.u[3] = hi ? P1w1 : x1;
      int slot = (s << 1) | hi;
      #pragma unroll
      for (int n = 0; n < 4; n++) {
        int rg = n * 32 + l31;
        short8 gf = *reinterpret_cast<const short8*>(
            gb + rg * 128 + ((slot ^ (rg & 7)) * 16));
        acc[n] = MFMA32(pf.s8, gf, acc[n]);
      }
    }
    __builtin_amdgcn_s_setprio(0);

    // write next tile into the other buffer (loads have had all of compute)
    if (t < 7) {
      char* pb2 = (char*)&phi_s[(t + 1) & 1][0][0];
      char* gb2 = (char*)&g_s[(t + 1) & 1][0][0];
      #pragma unroll
      for (int j = 0; j < 2; j++) {
        *reinterpret_cast<short8*>(pb2 + pr * 256 + (((pc2 + j) ^ (pr & 15)) * 16)) = sphi[j];
        *reinterpret_cast<short8*>(gb2 + gr * 128 + (((gc2 + j) ^ (gr & 7)) * 16)) = sg[j];
      }
    }
  }

  // exports: (m, l) per q and unnormalized partial acc
  float lsum = lpart + __shfl_xor(lpart, 32);
  if (lane < 32) {
    int q = q0 + wave * 32 + l31;
    pm[z * 32768 + b * 4096 + q] = mrun;
    pl[z * 32768 + b * 4096 + q] = lsum;
  }
  short* pacc = z ? pacc1 : pacc0;
  #pragma unroll
  for (int n = 0; n < 4; n++) {
    #pragma unroll
    for (int reg = 0; reg < 16; reg++) {
      int q = q0 + wave * 32 + (reg & 3) + 8 * (reg >> 2) + 4 * hi;
      pacc[((size_t)b * 4096 + q) * 128 + n * 32 + l31] = f2bf(acc[n][reg]);
    }
  }
}

// ---------------------------------------------------------------------------
// fused: merge KV-half partials -> y tile (LDS), then
// wy = w_w . y + bias, BN (eval), + x -> out fp32 [b][256][4096]
// 512 threads, 8 waves x 32 co, 128-q tiles, grid (32,8) = 256.
// ---------------------------------------------------------------------------
__global__ __launch_bounds__(512) void wconv_bn(
    const short* __restrict__ a0, const short* __restrict__ a1,
    const float* __restrict__ pm, const float* __restrict__ pl,
    const short* __restrict__ ww, const float* __restrict__ wb,
    const float* __restrict__ gamma, const float* __restrict__ beta,
    const float* __restrict__ mean, const float* __restrict__ var,
    const float* __restrict__ x, float* __restrict__ out)
{
  __shared__ short y_s[128][136];
  __shared__ float sc_s[256];
  __shared__ float sh_s[256];

  const int b = blockIdx.y;
  const int q0 = blockIdx.x * 128;
  const int tid = threadIdx.x;
  const int wave = tid >> 6, lane = tid & 63;
  const int lr = lane & 15, lg = lane >> 4;

  {
    int r = tid >> 2, c0 = (tid & 3) * 32;
    int iq = b * 4096 + q0 + r;
    float m0 = pm[iq], m1 = pm[32768 + iq];
    float l0 = pl[iq], l1 = pl[32768 + iq];
    float M = fmaxf(m0, m1);
    float w0 = __expf(m0 - M), w1 = __expf(m1 - M);
    float inv = 1.0f / (w0 * l0 + w1 * l1);
    w0 *= inv; w1 *= inv;
    size_t base = (size_t)iq * 128 + c0;
    #pragma unroll
    for (int j = 0; j < 4; j++) {
      short8 A0 = *reinterpret_cast<const short8*>(a0 + base + j * 8);
      short8 A1 = *reinterpret_cast<const short8*>(a1 + base + j * 8);
      short8 o;
      #pragma unroll
      for (int e = 0; e < 8; e++)
        o[e] = f2bf(w0 * bf2f(A0[e]) + w1 * bf2f(A1[e]));
      *reinterpret_cast<short8*>(&y_s[r][c0 + j * 8]) = o;
    }
    if (tid < 256) {
      float s = gamma[tid] * rsqrtf(var[tid] + 1e-5f);
      sc_s[tid] = s;
      sh_s[tid] = (wb[tid] - mean[tid]) * s + beta[tid];
    }
  }
  __syncthreads();

  f32x4 acc[2][8];
  #pragma unroll
  for (int m = 0; m < 2; m++)
    #pragma unroll
    for (int n = 0; n < 8; n++) acc[m][n] = (f32x4)0.0f;

  #pragma unroll
  for (int kk = 0; kk < 4; kk++) {
    short8 af[2], bfr[8];
    #pragma unroll
    for (int m = 0; m < 2; m++)
      af[m] = *reinterpret_cast<const short8*>(
          ww + (size_t)(wave * 32 + m * 16 + lr) * 128 + kk * 32 + lg * 8);
    #pragma unroll
    for (int n = 0; n < 8; n++)
      bfr[n] = *reinterpret_cast<const short8*>(&y_s[n * 16 + lr][kk * 32 + lg * 8]);
    #pragma unroll
    for (int m = 0; m < 2; m++)
      #pragma unroll
      for (int n = 0; n < 8; n++)
        acc[m][n] = MFMA16(af[m], bfr[n], acc[m][n]);
  }

  #pragma unroll
  for (int m = 0; m < 2; m++) {
    #pragma unroll
    for (int n = 0; n < 8; n++) {
      #pragma unroll
      for (int r = 0; r < 4; r++) {
        int co = wave * 32 + m * 16 + lg * 4 + r;
        int q = q0 + n * 16 + lr;
        size_t oidx = ((size_t)b * 256 + co) * 4096 + q;
        float v = acc[m][n][r] * sc_s[co] + sh_s[co];
        out[oidx] = v + x[oidx];
      }
    }
  }
}

// ---------------------------------------------------------------------------
extern "C" void kernel_launch(void* const* d_in, const int* in_sizes, int n_in,
                              void* d_out, int out_size, void* d_ws, size_t ws_size,
                              hipStream_t stream)
{
  const float* x    = (const float*)d_in[0];
  const float* nb   = (const float*)d_in[1];
  const float* g_w  = (const float*)d_in[2];
  const float* g_b  = (const float*)d_in[3];
  const float* th_w = (const float*)d_in[4];
  const float* th_b = (const float*)d_in[5];
  const float* ph_w = (const float*)d_in[6];
  const float* ph_b = (const float*)d_in[7];
  const float* w_w  = (const float*)d_in[8];
  const float* w_b  = (const float*)d_in[9];
  const float* gam  = (const float*)d_in[10];
  const float* bet  = (const float*)d_in[11];
  const float* mu   = (const float*)d_in[12];
  const float* var  = (const float*)d_in[13];
  float* out = (float*)d_out;

  char* ws = (char*)d_ws;
  short* theta_full = (short*)(ws);                        // 8 MB  [b][4096][128]
  short* pacc0      = (short*)(ws + (size_t)(8u << 20));   // 8 MB  [b][4096][128]
  short* pacc1      = (short*)(ws + (size_t)(16u << 20));  // 8 MB  [b][4096][128]
  short* phi_kc     = (short*)(ws + (size_t)(24u << 20));  // 2 MB  [b][1024][128]
  short* g_ck       = (short*)(ws + (size_t)(26u << 20));  // 2 MB  [b][128][1024]
  short* wts        = (short*)(ws + (size_t)(36u << 20));  // 256KB: th, ph, g, w
  float* pm         = (float*)(ws + (size_t)(37u << 20));  // 256KB [2][8][4096]
  float* pl         = (float*)(ws + (size_t)(38u << 20));  // 256KB [2][8][4096]
  short* th_wb = wts;
  short* ph_wb = wts + 32768;
  short* g_wb  = wts + 2 * 32768;
  short* w_wb  = wts + 3 * 32768;

  cvt_w<<<dim3(32, 4), 256, 0, stream>>>(th_w, ph_w, g_w, w_w, wts);
  conv_proj<2, 1><<<dim3(32, 8), 512, 0, stream>>>(nb, th_wb, th_b, ph_wb, ph_b,
                                                   theta_full, phi_kc);
  conv_proj<1, 2><<<dim3(32, 8), 512, 0, stream>>>(x, g_wb, g_b, nullptr, nullptr,
                                                   g_ck, nullptr);
  attn_split<<<dim3(16, 8, 2), 512, 0, stream>>>(theta_full, phi_kc, g_ck,
                                                 pacc0, pacc1, pm, pl);
  wconv_bn<<<dim3(32, 8), 512, 0, stream>>>(pacc0, pacc1, pm, pl,
                                            w_wb, w_b, gam, bet, mu, var, x, out);
}

// Round 10
// 82.440 us; speedup vs baseline: 1.4449x; 1.0839x over previous
//
#include <hip/hip_runtime.h>

typedef __attribute__((ext_vector_type(8))) short short8;
typedef __attribute__((ext_vector_type(4))) short short4v;
typedef __attribute__((ext_vector_type(4))) float f32x4;
typedef __attribute__((ext_vector_type(16))) float f32x16;
typedef __attribute__((ext_vector_type(4))) unsigned u32x4;

__device__ __forceinline__ float bf2f(short s) {
  union { unsigned u; float f; } cv;
  cv.u = ((unsigned)(unsigned short)s) << 16;
  return cv.f;
}
__device__ __forceinline__ short f2bf(float f) {
  union { float f; unsigned u; } cv;
  cv.f = f;
  unsigned r = (cv.u + 0x7fffu + ((cv.u >> 16) & 1u)) >> 16;
  return (short)(unsigned short)r;
}
__device__ __forceinline__ unsigned pk2(float a, float b) {
  return (unsigned)(unsigned short)f2bf(a) | ((unsigned)(unsigned short)f2bf(b) << 16);
}

#define MFMA16(a, b, c) __builtin_amdgcn_mfma_f32_16x16x32_bf16((a), (b), (c), 0, 0, 0)
#define MFMA32(a, b, c) __builtin_amdgcn_mfma_f32_32x32x16_bf16((a), (b), (c), 0, 0, 0)

// ---------------------------------------------------------------------------
// convert fp32 weight matrices -> bf16 workspace. 4 matrices x 32768 elems.
// ---------------------------------------------------------------------------
__global__ __launch_bounds__(256) void cvt_w(
    const float* __restrict__ s0, const float* __restrict__ s1,
    const float* __restrict__ s2, const float* __restrict__ s3,
    short* __restrict__ d)
{
  const float* srcs[4] = {s0, s1, s2, s3};
  const float* s = srcs[blockIdx.y];
  int i = (blockIdx.x * 256 + threadIdx.x) * 4;
  f32x4 v = *reinterpret_cast<const f32x4*>(s + i);
  short4v o;
  #pragma unroll
  for (int j = 0; j < 4; j++) o[j] = f2bf(v[j]);
  *reinterpret_cast<short4v*>(d + (size_t)blockIdx.y * 32768 + i) = o;
}

// ---------------------------------------------------------------------------
// conv1x1 body (+ optional fused 2x2 maxpool epilogues).  Pixel<->M-row
// permutation puts a pooled cell's 4 pixels in one lane's f32x4 (exact).
// MODE: 0 full-res [b][p][o]; 1 pooled [b][kp][o]; 2 pooled-T [b][o][kp].
// ---------------------------------------------------------------------------
template <int NPROJ, int MODE1>
__device__ __forceinline__ void conv_body(
    short (*in_t)[40], short (*wt)[40],
    const float* __restrict__ in,
    const short* __restrict__ w0, const float* __restrict__ bias0,
    const short* __restrict__ w1, const float* __restrict__ bias1,
    short* __restrict__ out0, short* __restrict__ out1)
{
  const int b = blockIdx.y;
  const int p0 = blockIdx.x * 128;
  const int tid = threadIdx.x;
  const int wave = tid >> 6, lane = tid & 63;
  const int lr = lane & 15, lg = lane >> 4;

  const short* wsrc[2] = {w0, w1};

  f32x4 acc[NPROJ][8];
  #pragma unroll
  for (int pj = 0; pj < NPROJ; pj++)
    #pragma unroll
    for (int n = 0; n < 8; n++) acc[pj][n] = (f32x4)0.0f;

  for (int kc = 0; kc < 256; kc += 32) {
    __syncthreads();
    {
      int c = tid >> 4;                 // 0..31
      int pg = (tid & 15) * 8;          // global pixel group 0..120
      const float* src = in + ((size_t)(b * 256 + kc + c)) * 4096 + p0 + pg;
      f32x4 v0 = *reinterpret_cast<const f32x4*>(src);
      f32x4 v1 = *reinterpret_cast<const f32x4*>(src + 4);
      #pragma unroll
      for (int j = 0; j < 8; j++) {
        int p = pg + j;
        int a = ((p & 63) >> 1) * 4 + ((p >> 6) << 1) + (p & 1);
        float fv = (j < 4) ? v0[j] : v1[j - 4];
        in_t[a][c ^ ((((a >> 3) & 3)) << 3)] = f2bf(fv);
      }
    }
    if (tid < NPROJ * 128) {
      int pj = tid >> 7, o = tid & 127;
      const short8* src = reinterpret_cast<const short8*>(wsrc[pj] + (size_t)o * 256 + kc);
      int f = (o >> 3) & 3;
      #pragma unroll
      for (int gq = 0; gq < 4; gq++)
        *reinterpret_cast<short8*>(&wt[pj * 128 + o][(gq ^ f) * 8]) = src[gq];
    }
    __syncthreads();

    int arow = wave * 16 + lr;
    short8 afrag = *reinterpret_cast<const short8*>(
        &in_t[arow][(lg ^ ((arow >> 3) & 3)) * 8]);
    #pragma unroll
    for (int pj = 0; pj < NPROJ; pj++) {
      #pragma unroll
      for (int n = 0; n < 8; n++) {
        int brow = n * 16 + lr;
        short8 bfrag = *reinterpret_cast<const short8*>(
            &wt[pj * 128 + brow][(lg ^ ((brow >> 3) & 3)) * 8]);
        acc[pj][n] = MFMA16(afrag, bfrag, acc[pj][n]);
      }
    }
  }

  const float* bsrc[2] = {bias0, bias1};
  short* osrc[2] = {out0, out1};
  const int kp = blockIdx.x * 32 + wave * 4 + lg;
  #pragma unroll
  for (int pj = 0; pj < NPROJ; pj++) {
    const int mode = (pj == 0 && NPROJ == 2) ? 0 : MODE1;
    #pragma unroll
    for (int n = 0; n < 8; n++) {
      int o = n * 16 + lr;
      float bv = bsrc[pj][o];
      if (mode == 0) {
        #pragma unroll
        for (int r = 0; r < 4; r++) {
          int pix = (wave * 4 + lg) * 2 + (r & 1) + ((r >> 1) & 1) * 64;
          osrc[pj][((size_t)b * 4096 + p0 + pix) * 128 + o] = f2bf(acc[pj][n][r] + bv);
        }
      } else {
        f32x4 v = acc[pj][n];
        float pv = fmaxf(fmaxf(v[0], v[1]), fmaxf(v[2], v[3])) + bv;
        if (mode == 1)
          osrc[pj][((size_t)b * 1024 + kp) * 128 + o] = f2bf(pv);
        else
          osrc[pj][((size_t)b * 128 + o) * 1024 + kp] = f2bf(pv);
      }
    }
  }
}

// fused conv dispatch: z=0 -> theta(full)+phi(pooled) from nb;
//                      z=1 -> g (pooled-T) from x.  2 blocks/CU.
__global__ __launch_bounds__(512, 4) void conv_all(
    const float* __restrict__ nb, const float* __restrict__ x,
    const short* __restrict__ th_w, const float* __restrict__ th_b,
    const short* __restrict__ ph_w, const float* __restrict__ ph_b,
    const short* __restrict__ g_w, const float* __restrict__ g_b,
    short* __restrict__ theta, short* __restrict__ phi_kc,
    short* __restrict__ g_ck)
{
  __shared__ short in_t[128][40];
  __shared__ short wt[256][40];
  if (blockIdx.z == 0)
    conv_body<2, 1>(in_t, wt, nb, th_w, th_b, ph_w, ph_b, theta, phi_kc);
  else
    conv_body<1, 2>(in_t, wt, x, g_w, g_b, nullptr, nullptr, g_ck, nullptr);
}

// ---------------------------------------------------------------------------
// flash attention v8: in-block split-KV.  QBLK=128; waves 0-3 kv[0,512),
// waves 4-7 kv[512,1024).  32x32 MFMA, in-register P, double-buffered
// per-z phi/g tiles (128KB LDS), fp32 in-LDS merge, writes final y bf16.
// Grid (32, 8) = 256 blocks, 512 threads.
// ---------------------------------------------------------------------------
__global__ __launch_bounds__(512) void attn(
    const short* __restrict__ theta, const short* __restrict__ phi,
    const short* __restrict__ g, short* __restrict__ y)
{
  __shared__ char lds[131072];          // phi: (buf*2+z)*16384 ; g: +65536
  __shared__ float ml[8][32][2];

  const int b = blockIdx.y;
  const int q0 = blockIdx.x * 128;
  const int tid = threadIdx.x;
  const int wave = tid >> 6, lane = tid & 63;
  const int l31 = lane & 31, hi = lane >> 5;
  const int zw = wave >> 2, wq = wave & 3;

  // theta B-fragments: lane holds theta[q = l31][k = s*16 + hi*8 + j]
  short8 ath[8];
  {
    const short* tq = theta + ((size_t)b * 4096 + q0 + wq * 32 + l31) * 128 + hi * 8;
    #pragma unroll
    for (int s = 0; s < 8; s++)
      ath[s] = *reinterpret_cast<const short8*>(tq + s * 16);
  }

  // staging: threads 0-255 stage z=0 tiles, 256-511 z=1 (64B phi + 64B g each)
  const int t8 = tid & 255, zs = tid >> 8;
  const int pr = t8 >> 2, pcq = t8 & 3;
  const int gr = t8 >> 1, ghq = t8 & 1;
  const short* phi_src = phi + ((size_t)b * 1024 + zs * 512 + pr) * 128 + pcq * 32;
  const short* g_src   = g + ((size_t)b * 128 + gr) * 1024 + zs * 512 + ghq * 32;

  short8 sphi[4], sg[4];
  #pragma unroll
  for (int j = 0; j < 4; j++) {
    sphi[j] = *reinterpret_cast<const short8*>(phi_src + j * 8);
    sg[j]   = *reinterpret_cast<const short8*>(g_src + j * 8);
  }

  float mrun = -1e30f, lpart = 0.0f;
  f32x16 acc[4];
  #pragma unroll
  for (int n = 0; n < 4; n++) acc[n] = (f32x16)0.0f;

  // prologue: write tile 0 into buf 0 (own staging z)
  {
    char* pb = lds + zs * 16384;
    char* gb = lds + 65536 + zs * 16384;
    #pragma unroll
    for (int j = 0; j < 4; j++) {
      *reinterpret_cast<short8*>(pb + pr * 256 + (((pcq * 4 + j) ^ (pr & 15)) * 16)) = sphi[j];
      *reinterpret_cast<short8*>(gb + gr * 128 + (((ghq * 4 + j) ^ (gr & 7)) * 16)) = sg[j];
    }
  }

  for (int t = 0; t < 8; t++) {
    __syncthreads();
    char* pb = lds + ((t & 1) * 2 + zw) * 16384;
    char* gb = lds + 65536 + ((t & 1) * 2 + zw) * 16384;

    if (t < 7) {
      const short* ps = phi_src + (t + 1) * 64 * 128;
      const short* gs = g_src + (t + 1) * 64;
      #pragma unroll
      for (int j = 0; j < 4; j++) {
        sphi[j] = *reinterpret_cast<const short8*>(ps + j * 8);
        sg[j]   = *reinterpret_cast<const short8*>(gs + j * 8);
      }
    }

    // QK^T: S^T 32x32 tiles (rows kv, cols q = l31)
    f32x16 facc0 = (f32x16)0.0f, facc1 = (f32x16)0.0f;
    __builtin_amdgcn_s_setprio(1);
    #pragma unroll
    for (int s = 0; s < 8; s++) {
      int slot = (s << 1) | hi;
      short8 pf0 = *reinterpret_cast<const short8*>(
          pb + l31 * 256 + ((slot ^ (l31 & 15)) * 16));
      short8 pf1 = *reinterpret_cast<const short8*>(
          pb + (32 + l31) * 256 + ((slot ^ (l31 & 15)) * 16));
      facc0 = MFMA32(pf0, ath[s], facc0);
      facc1 = MFMA32(pf1, ath[s], facc1);
    }
    __builtin_amdgcn_s_setprio(0);

    // online softmax (lane owns q = l31)
    float m = facc0[0];
    #pragma unroll
    for (int r = 1; r < 16; r++) m = fmaxf(m, facc0[r]);
    #pragma unroll
    for (int r = 0; r < 16; r++) m = fmaxf(m, facc1[r]);
    m = fmaxf(m, __shfl_xor(m, 32));
    if (__any(m - mrun > 10.0f)) {
      float mn = fmaxf(mrun, m);
      float sc = __expf(mrun - mn);
      mrun = mn;
      lpart *= sc;
      #pragma unroll
      for (int reg = 0; reg < 16; reg++) {
        int qr = (reg & 3) + 8 * (reg >> 2) + 4 * hi;
        float sr = __shfl(sc, qr);
        #pragma unroll
        for (int n = 0; n < 4; n++) acc[n][reg] *= sr;
      }
    }
    float ls = 0.0f;
    #pragma unroll
    for (int r = 0; r < 16; r++) { facc0[r] = __expf(facc0[r] - mrun); ls += facc0[r]; }
    #pragma unroll
    for (int r = 0; r < 16; r++) { facc1[r] = __expf(facc1[r] - mrun); ls += facc1[r]; }
    lpart += ls;

    // PV with in-register P assembly (own 4 + partner 4 via shfl_xor 32)
    __builtin_amdgcn_s_setprio(1);
    #pragma unroll
    for (int s = 0; s < 4; s++) {
      const int base = (s & 1) * 8;
      float p0, p1, p2, p3, p4, p5, p6, p7;
      if (s < 2) {
        p0 = facc0[base + 0]; p1 = facc0[base + 1]; p2 = facc0[base + 2]; p3 = facc0[base + 3];
        p4 = facc0[base + 4]; p5 = facc0[base + 5]; p6 = facc0[base + 6]; p7 = facc0[base + 7];
      } else {
        p0 = facc1[base + 0]; p1 = facc1[base + 1]; p2 = facc1[base + 2]; p3 = facc1[base + 3];
        p4 = facc1[base + 4]; p5 = facc1[base + 5]; p6 = facc1[base + 6]; p7 = facc1[base + 7];
      }
      unsigned P0w0 = pk2(p0, p1), P0w1 = pk2(p2, p3);
      unsigned P1w0 = pk2(p4, p5), P1w1 = pk2(p6, p7);
      unsigned x0 = (unsigned)__shfl_xor((int)P0w0, 32);
      unsigned x1 = (unsigned)__shfl_xor((int)P0w1, 32);
      unsigned y0 = (unsigned)__shfl_xor((int)P1w0, 32);
      unsigned y1 = (unsigned)__shfl_xor((int)P1w1, 32);
      union { u32x4 u; short8 s8; } pf;
      pf.u[0] = hi ? y0 : P0w0;
      pf.u[1] = hi ? y1 : P0w1;
      pf.u[2] = hi ? P1w0 : x0;
      pf.u[3] = hi ? P1w1 : x1;
      int slot = (s << 1) | hi;
      #pragma unroll
      for (int n = 0; n < 4; n++) {
        int rg = n * 32 + l31;
        short8 gf = *reinterpret_cast<const short8*>(
            gb + rg * 128 + ((slot ^ (rg & 7)) * 16));
        acc[n] = MFMA32(pf.s8, gf, acc[n]);
      }
    }
    __builtin_amdgcn_s_setprio(0);

    if (t < 7) {
      char* pb2 = lds + (((t + 1) & 1) * 2 + zs) * 16384;
      char* gb2 = lds + 65536 + (((t + 1) & 1) * 2 + zs) * 16384;
      #pragma unroll
      for (int j = 0; j < 4; j++) {
        *reinterpret_cast<short8*>(pb2 + pr * 256 + (((pcq * 4 + j) ^ (pr & 15)) * 16)) = sphi[j];
        *reinterpret_cast<short8*>(gb2 + gr * 128 + (((ghq * 4 + j) ^ (gr & 7)) * 16)) = sg[j];
      }
    }
  }

  // ---- in-block merge of the two kv halves ----
  float lsum = lpart + __shfl_xor(lpart, 32);
  if (lane < 32) { ml[wave][l31][0] = mrun; ml[wave][l31][1] = lsum; }
  __syncthreads();
  float mo = ml[wave ^ 4][l31][0];
  float lo = ml[wave ^ 4][l31][1];
  float M = fmaxf(mrun, mo);
  float e0 = __expf(mrun - M), e1 = __expf(mo - M);
  float wown = e0 / (e0 * lsum + e1 * lo);   // normalized weight for own partial
  #pragma unroll
  for (int reg = 0; reg < 16; reg++) {
    int qr = (reg & 3) + 8 * (reg >> 2) + 4 * hi;
    float wr = __shfl(wown, qr);
    #pragma unroll
    for (int n = 0; n < 4; n++) acc[n][reg] *= wr;
  }
  float* mb = (float*)(lds + wq * 16384);    // 16KB per pair, overlays phi bufs
  if (zw == 1) {
    #pragma unroll
    for (int n = 0; n < 4; n++)
      #pragma unroll
      for (int reg = 0; reg < 16; reg++) {
        int qrow = (reg & 3) + 8 * (reg >> 2) + 4 * hi;
        mb[qrow * 128 + n * 32 + l31] = acc[n][reg];
      }
  }
  __syncthreads();
  if (zw == 0) {
    #pragma unroll
    for (int n = 0; n < 4; n++)
      #pragma unroll
      for (int reg = 0; reg < 16; reg++) {
        int qrow = (reg & 3) + 8 * (reg >> 2) + 4 * hi;
        float v = acc[n][reg] + mb[qrow * 128 + n * 32 + l31];
        y[((size_t)b * 4096 + q0 + wq * 32 + qrow) * 128 + n * 32 + l31] = f2bf(v);
      }
  }
}

// ---------------------------------------------------------------------------
// wy = w_w . y + bias, BN (eval), + x -> out fp32 [b][256][4096]
// 512 threads, 8 waves x 32 co, 128-q tiles, grid (32,8) = 256.
// ---------------------------------------------------------------------------
__global__ __launch_bounds__(512) void wconv_bn(
    const short* __restrict__ yb, const short* __restrict__ ww,
    const float* __restrict__ wb,
    const float* __restrict__ gamma, const float* __restrict__ beta,
    const float* __restrict__ mean, const float* __restrict__ var,
    const float* __restrict__ x, float* __restrict__ out)
{
  __shared__ short y_s[128][136];
  __shared__ float sc_s[256];
  __shared__ float sh_s[256];

  const int b = blockIdx.y;
  const int q0 = blockIdx.x * 128;
  const int tid = threadIdx.x;
  const int wave = tid >> 6, lane = tid & 63;
  const int lr = lane & 15, lg = lane >> 4;

  {
    int r = tid >> 2, c0 = (tid & 3) * 32;
    const short8* src = reinterpret_cast<const short8*>(
        yb + ((size_t)(b * 4096 + q0 + r)) * 128 + c0);
    short8* dst = reinterpret_cast<short8*>(&y_s[r][c0]);
    #pragma unroll
    for (int j = 0; j < 4; j++) dst[j] = src[j];
    if (tid < 256) {
      float s = gamma[tid] * rsqrtf(var[tid] + 1e-5f);
      sc_s[tid] = s;
      sh_s[tid] = (wb[tid] - mean[tid]) * s + beta[tid];
    }
  }
  __syncthreads();

  f32x4 acc[2][8];
  #pragma unroll
  for (int m = 0; m < 2; m++)
    #pragma unroll
    for (int n = 0; n < 8; n++) acc[m][n] = (f32x4)0.0f;

  #pragma unroll
  for (int kk = 0; kk < 4; kk++) {
    short8 af[2], bfr[8];
    #pragma unroll
    for (int m = 0; m < 2; m++)
      af[m] = *reinterpret_cast<const short8*>(
          ww + (size_t)(wave * 32 + m * 16 + lr) * 128 + kk * 32 + lg * 8);
    #pragma unroll
    for (int n = 0; n < 8; n++)
      bfr[n] = *reinterpret_cast<const short8*>(&y_s[n * 16 + lr][kk * 32 + lg * 8]);
    #pragma unroll
    for (int m = 0; m < 2; m++)
      #pragma unroll
      for (int n = 0; n < 8; n++)
        acc[m][n] = MFMA16(af[m], bfr[n], acc[m][n]);
  }

  #pragma unroll
  for (int m = 0; m < 2; m++) {
    #pragma unroll
    for (int n = 0; n < 8; n++) {
      #pragma unroll
      for (int r = 0; r < 4; r++) {
        int co = wave * 32 + m * 16 + lg * 4 + r;
        int q = q0 + n * 16 + lr;
        size_t oidx = ((size_t)b * 256 + co) * 4096 + q;
        float v = acc[m][n][r] * sc_s[co] + sh_s[co];
        out[oidx] = v + x[oidx];
      }
    }
  }
}

// ---------------------------------------------------------------------------
extern "C" void kernel_launch(void* const* d_in, const int* in_sizes, int n_in,
                              void* d_out, int out_size, void* d_ws, size_t ws_size,
                              hipStream_t stream)
{
  const float* x    = (const float*)d_in[0];
  const float* nb   = (const float*)d_in[1];
  const float* g_w  = (const float*)d_in[2];
  const float* g_b  = (const float*)d_in[3];
  const float* th_w = (const float*)d_in[4];
  const float* th_b = (const float*)d_in[5];
  const float* ph_w = (const float*)d_in[6];
  const float* ph_b = (const float*)d_in[7];
  const float* w_w  = (const float*)d_in[8];
  const float* w_b  = (const float*)d_in[9];
  const float* gam  = (const float*)d_in[10];
  const float* bet  = (const float*)d_in[11];
  const float* mu   = (const float*)d_in[12];
  const float* var  = (const float*)d_in[13];
  float* out = (float*)d_out;

  char* ws = (char*)d_ws;
  short* theta_full = (short*)(ws);                        // 8 MB  [b][4096][128]
  short* yb         = (short*)(ws + (size_t)(8u << 20));   // 8 MB  [b][4096][128]
  short* phi_kc     = (short*)(ws + (size_t)(16u << 20));  // 2 MB  [b][1024][128]
  short* g_ck       = (short*)(ws + (size_t)(18u << 20));  // 2 MB  [b][128][1024]
  short* wts        = (short*)(ws + (size_t)(20u << 20));  // 256KB: th, ph, g, w
  short* th_wb = wts;
  short* ph_wb = wts + 32768;
  short* g_wb  = wts + 2 * 32768;
  short* w_wb  = wts + 3 * 32768;

  cvt_w<<<dim3(32, 4), 256, 0, stream>>>(th_w, ph_w, g_w, w_w, wts);
  conv_all<<<dim3(32, 8, 2), 512, 0, stream>>>(nb, x, th_wb, th_b, ph_wb, ph_b,
                                               g_wb, g_b, theta_full, phi_kc, g_ck);
  attn<<<dim3(32, 8), 512, 0, stream>>>(theta_full, phi_kc, g_ck, yb);
  wconv_bn<<<dim3(32, 8), 512, 0, stream>>>(yb, w_wb, w_b, gam, bet, mu, var, x, out);
}

// Round 11
// 82.382 us; speedup vs baseline: 1.4459x; 1.0007x over previous
//
#include <hip/hip_runtime.h>

typedef __attribute__((ext_vector_type(8))) short short8;
typedef __attribute__((ext_vector_type(4))) short short4v;
typedef __attribute__((ext_vector_type(4))) float f32x4;
typedef __attribute__((ext_vector_type(16))) float f32x16;
typedef __attribute__((ext_vector_type(4))) unsigned u32x4;

__device__ __forceinline__ float bf2f(short s) {
  union { unsigned u; float f; } cv;
  cv.u = ((unsigned)(unsigned short)s) << 16;
  return cv.f;
}
__device__ __forceinline__ short f2bf(float f) {
  union { float f; unsigned u; } cv;
  cv.f = f;
  unsigned r = (cv.u + 0x7fffu + ((cv.u >> 16) & 1u)) >> 16;
  return (short)(unsigned short)r;
}
// packed RNE f32x2 -> bf16x2 (lo = a, hi = b) in one VALU op
__device__ __forceinline__ unsigned cvtpk(float a, float b) {
  unsigned r;
  asm("v_cvt_pk_bf16_f32 %0, %1, %2" : "=v"(r) : "v"(a), "v"(b));
  return r;
}
// async global->LDS, 16B/lane, lane i lands at ldsbase + i*16
__device__ __forceinline__ void load_lds16(const void* g, void* l) {
  __builtin_amdgcn_global_load_lds(
      (const __attribute__((address_space(1))) void*)g,
      (__attribute__((address_space(3))) void*)l, 16, 0, 0);
}

#define MFMA16(a, b, c) __builtin_amdgcn_mfma_f32_16x16x32_bf16((a), (b), (c), 0, 0, 0)
#define MFMA32(a, b, c) __builtin_amdgcn_mfma_f32_32x32x16_bf16((a), (b), (c), 0, 0, 0)

// ---------------------------------------------------------------------------
// convert fp32 weight matrices -> bf16 workspace. 4 matrices x 32768 elems.
// ---------------------------------------------------------------------------
__global__ __launch_bounds__(256) void cvt_w(
    const float* __restrict__ s0, const float* __restrict__ s1,
    const float* __restrict__ s2, const float* __restrict__ s3,
    short* __restrict__ d)
{
  const float* srcs[4] = {s0, s1, s2, s3};
  const float* s = srcs[blockIdx.y];
  int i = (blockIdx.x * 256 + threadIdx.x) * 4;
  f32x4 v = *reinterpret_cast<const f32x4*>(s + i);
  short4v o;
  #pragma unroll
  for (int j = 0; j < 4; j++) o[j] = f2bf(v[j]);
  *reinterpret_cast<short4v*>(d + (size_t)blockIdx.y * 32768 + i) = o;
}

// ---------------------------------------------------------------------------
// conv1x1 body (+ optional fused 2x2 maxpool epilogues).  Pixel<->M-row
// permutation puts a pooled cell's 4 pixels in one lane's f32x4 (exact).
// MODE: 0 full-res [b][p][o]; 1 pooled [b][kp][o]; 2 pooled-T [b][o][kp].
// ---------------------------------------------------------------------------
template <int NPROJ, int MODE1>
__device__ __forceinline__ void conv_body(
    short (*in_t)[40], short (*wt)[40],
    const float* __restrict__ in,
    const short* __restrict__ w0, const float* __restrict__ bias0,
    const short* __restrict__ w1, const float* __restrict__ bias1,
    short* __restrict__ out0, short* __restrict__ out1)
{
  const int b = blockIdx.y;
  const int p0 = blockIdx.x * 128;
  const int tid = threadIdx.x;
  const int wave = tid >> 6, lane = tid & 63;
  const int lr = lane & 15, lg = lane >> 4;

  const short* wsrc[2] = {w0, w1};

  f32x4 acc[NPROJ][8];
  #pragma unroll
  for (int pj = 0; pj < NPROJ; pj++)
    #pragma unroll
    for (int n = 0; n < 8; n++) acc[pj][n] = (f32x4)0.0f;

  for (int kc = 0; kc < 256; kc += 32) {
    __syncthreads();
    {
      int c = tid >> 4;                 // 0..31
      int pg = (tid & 15) * 8;          // global pixel group 0..120
      const float* src = in + ((size_t)(b * 256 + kc + c)) * 4096 + p0 + pg;
      f32x4 v0 = *reinterpret_cast<const f32x4*>(src);
      f32x4 v1 = *reinterpret_cast<const f32x4*>(src + 4);
      #pragma unroll
      for (int j = 0; j < 8; j++) {
        int p = pg + j;
        int a = ((p & 63) >> 1) * 4 + ((p >> 6) << 1) + (p & 1);
        float fv = (j < 4) ? v0[j] : v1[j - 4];
        in_t[a][c ^ ((((a >> 3) & 3)) << 3)] = f2bf(fv);
      }
    }
    if (tid < NPROJ * 128) {
      int pj = tid >> 7, o = tid & 127;
      const short8* src = reinterpret_cast<const short8*>(wsrc[pj] + (size_t)o * 256 + kc);
      int f = (o >> 3) & 3;
      #pragma unroll
      for (int gq = 0; gq < 4; gq++)
        *reinterpret_cast<short8*>(&wt[pj * 128 + o][(gq ^ f) * 8]) = src[gq];
    }
    __syncthreads();

    int arow = wave * 16 + lr;
    short8 afrag = *reinterpret_cast<const short8*>(
        &in_t[arow][(lg ^ ((arow >> 3) & 3)) * 8]);
    #pragma unroll
    for (int pj = 0; pj < NPROJ; pj++) {
      #pragma unroll
      for (int n = 0; n < 8; n++) {
        int brow = n * 16 + lr;
        short8 bfrag = *reinterpret_cast<const short8*>(
            &wt[pj * 128 + brow][(lg ^ ((brow >> 3) & 3)) * 8]);
        acc[pj][n] = MFMA16(afrag, bfrag, acc[pj][n]);
      }
    }
  }

  const float* bsrc[2] = {bias0, bias1};
  short* osrc[2] = {out0, out1};
  const int kp = blockIdx.x * 32 + wave * 4 + lg;
  #pragma unroll
  for (int pj = 0; pj < NPROJ; pj++) {
    const int mode = (pj == 0 && NPROJ == 2) ? 0 : MODE1;
    #pragma unroll
    for (int n = 0; n < 8; n++) {
      int o = n * 16 + lr;
      float bv = bsrc[pj][o];
      if (mode == 0) {
        #pragma unroll
        for (int r = 0; r < 4; r++) {
          int pix = (wave * 4 + lg) * 2 + (r & 1) + ((r >> 1) & 1) * 64;
          osrc[pj][((size_t)b * 4096 + p0 + pix) * 128 + o] = f2bf(acc[pj][n][r] + bv);
        }
      } else {
        f32x4 v = acc[pj][n];
        float pv = fmaxf(fmaxf(v[0], v[1]), fmaxf(v[2], v[3])) + bv;
        if (mode == 1)
          osrc[pj][((size_t)b * 1024 + kp) * 128 + o] = f2bf(pv);
        else
          osrc[pj][((size_t)b * 128 + o) * 1024 + kp] = f2bf(pv);
      }
    }
  }
}

// fused conv dispatch: z=0 -> theta(full)+phi(pooled) from nb;
//                      z=1 -> g (pooled-T) from x.  2 blocks/CU.
__global__ __launch_bounds__(512, 4) void conv_all(
    const float* __restrict__ nb, const float* __restrict__ x,
    const short* __restrict__ th_w, const float* __restrict__ th_b,
    const short* __restrict__ ph_w, const float* __restrict__ ph_b,
    const short* __restrict__ g_w, const float* __restrict__ g_b,
    short* __restrict__ theta, short* __restrict__ phi_kc,
    short* __restrict__ g_ck)
{
  __shared__ short in_t[128][40];
  __shared__ short wt[256][40];
  if (blockIdx.z == 0)
    conv_body<2, 1>(in_t, wt, nb, th_w, th_b, ph_w, ph_b, theta, phi_kc);
  else
    conv_body<1, 2>(in_t, wt, x, g_w, g_b, nullptr, nullptr, g_ck, nullptr);
}

// ---------------------------------------------------------------------------
// flash attention v9: in-block split-KV, global_load_lds staging with
// pre-swizzled sources (linear LDS dest, swizzled read — involution both
// sides), tree max/sum, cvt_pk P-packing.  QBLK=128; waves 0-3 kv[0,512),
// waves 4-7 kv[512,1024).  32x32 MFMA, in-register P exchange.
// Grid (32, 8) = 256 blocks, 512 threads.
// ---------------------------------------------------------------------------
__global__ __launch_bounds__(512) void attn(
    const short* __restrict__ theta, const short* __restrict__ phi,
    const short* __restrict__ g, short* __restrict__ y)
{
  __shared__ char lds[131072];          // phi: (buf*2+z)*16384 ; g: +65536
  __shared__ float ml[8][32][2];

  const int b = blockIdx.y;
  const int q0 = blockIdx.x * 128;
  const int tid = threadIdx.x;
  const int wave = tid >> 6, lane = tid & 63;
  const int l31 = lane & 31, hi = lane >> 5;
  const int zw = wave >> 2, wq = wave & 3;

  // theta B-fragments: lane holds theta[q = l31][k = s*16 + hi*8 + j]
  short8 ath[8];
  {
    const short* tq = theta + ((size_t)b * 4096 + q0 + wq * 32 + l31) * 128 + hi * 8;
    #pragma unroll
    for (int s = 0; s < 8; s++)
      ath[s] = *reinterpret_cast<const short8*>(tq + s * 16);
  }

  // ---- per-wave gload_lds staging setup (wave stages its own z = zw) ----
  // phi tile (16KB/z): wave quarter wq covers LDS [wq*4096, +4096), 4 instrs.
  //   lane l, instr i: LDS row r = wq*16 + i*4 + (l>>4), slot s = l&15;
  //   source = row r, global slot (s ^ (r&15))  [involution with read side]
  const short* psrc[4];
  {
    int rb = wq * 16 + (lane >> 4), sl = lane & 15;
    #pragma unroll
    for (int i = 0; i < 4; i++) {
      int r = rb + i * 4;
      psrc[i] = phi + ((size_t)b * 1024 + zw * 512 + r) * 128 + ((sl ^ (r & 15)) * 8);
    }
  }
  // g tile (16KB/z): rows ci; lane l, instr i: row r = wq*32 + i*8 + (l>>3),
  //   slot s = l&7; source = g row r, kv slot (s ^ (r&7))
  const short* gsrc[4];
  {
    int rb = wq * 32 + (lane >> 3), sl = lane & 7;
    #pragma unroll
    for (int i = 0; i < 4; i++) {
      int r = rb + i * 8;
      gsrc[i] = g + ((size_t)b * 128 + r) * 1024 + zw * 512 + ((sl ^ (r & 7)) * 8);
    }
  }

  float mrun = -1e30f, lpart = 0.0f;
  f32x16 acc[4];
  #pragma unroll
  for (int n = 0; n < 4; n++) acc[n] = (f32x16)0.0f;

  // prologue: issue tile 0 into buf 0 (drained by first barrier)
  {
    char* pb = lds + zw * 16384 + wq * 4096;
    char* gb = lds + 65536 + zw * 16384 + wq * 4096;
    #pragma unroll
    for (int i = 0; i < 4; i++) {
      load_lds16(psrc[i], pb + i * 1024);
      load_lds16(gsrc[i], gb + i * 1024);
    }
  }

  for (int t = 0; t < 8; t++) {
    __syncthreads();   // drains vmcnt -> buf[t&1] ready; frees buf[(t+1)&1]
    char* pb = lds + ((t & 1) * 2 + zw) * 16384;
    char* gb = lds + 65536 + ((t & 1) * 2 + zw) * 16384;

    // issue tile t+1 direct to LDS (lands under compute, drained next barrier)
    if (t < 7) {
      char* pb2 = lds + (((t + 1) & 1) * 2 + zw) * 16384 + wq * 4096;
      char* gb2 = lds + 65536 + (((t + 1) & 1) * 2 + zw) * 16384 + wq * 4096;
      #pragma unroll
      for (int i = 0; i < 4; i++) {
        load_lds16(psrc[i] + (t + 1) * 8192, pb2 + i * 1024);
        load_lds16(gsrc[i] + (t + 1) * 64, gb2 + i * 1024);
      }
    }

    // QK^T: S^T 32x32 tiles (rows kv, cols q = l31)
    f32x16 facc0 = (f32x16)0.0f, facc1 = (f32x16)0.0f;
    __builtin_amdgcn_s_setprio(1);
    #pragma unroll
    for (int s = 0; s < 8; s++) {
      int slot = (s << 1) | hi;
      short8 pf0 = *reinterpret_cast<const short8*>(
          pb + l31 * 256 + ((slot ^ (l31 & 15)) * 16));
      short8 pf1 = *reinterpret_cast<const short8*>(
          pb + (32 + l31) * 256 + ((slot ^ (l31 & 15)) * 16));
      facc0 = MFMA32(pf0, ath[s], facc0);
      facc1 = MFMA32(pf1, ath[s], facc1);
    }
    __builtin_amdgcn_s_setprio(0);

    // online softmax (lane owns q = l31): depth-5 max tree
    float mv[16];
    #pragma unroll
    for (int r = 0; r < 16; r++) mv[r] = fmaxf(facc0[r], facc1[r]);
    #pragma unroll
    for (int s = 8; s >= 1; s >>= 1)
      #pragma unroll
      for (int r = 0; r < s; r++) mv[r] = fmaxf(mv[r], mv[r + s]);
    float m = fmaxf(mv[0], __shfl_xor(mv[0], 32));

    if (__any(m - mrun > 10.0f)) {
      float mn = fmaxf(mrun, m);
      float sc = __expf(mrun - mn);
      mrun = mn;
      lpart *= sc;
      #pragma unroll
      for (int reg = 0; reg < 16; reg++) {
        int qr = (reg & 3) + 8 * (reg >> 2) + 4 * hi;
        float sr = __shfl(sc, qr);
        #pragma unroll
        for (int n = 0; n < 4; n++) acc[n][reg] *= sr;
      }
    }
    // P = exp(S - m) in place; depth-5 sum tree
    #pragma unroll
    for (int r = 0; r < 16; r++) facc0[r] = __expf(facc0[r] - mrun);
    #pragma unroll
    for (int r = 0; r < 16; r++) facc1[r] = __expf(facc1[r] - mrun);
    {
      float sv[16];
      #pragma unroll
      for (int r = 0; r < 16; r++) sv[r] = facc0[r] + facc1[r];
      #pragma unroll
      for (int s = 8; s >= 1; s >>= 1)
        #pragma unroll
        for (int r = 0; r < s; r++) sv[r] += sv[r + s];
      lpart += sv[0];
    }

    // PV with in-register P assembly (own 4 + partner 4 via shfl_xor 32)
    __builtin_amdgcn_s_setprio(1);
    #pragma unroll
    for (int s = 0; s < 4; s++) {
      const int base = (s & 1) * 8;
      float p0, p1, p2, p3, p4, p5, p6, p7;
      if (s < 2) {
        p0 = facc0[base + 0]; p1 = facc0[base + 1]; p2 = facc0[base + 2]; p3 = facc0[base + 3];
        p4 = facc0[base + 4]; p5 = facc0[base + 5]; p6 = facc0[base + 6]; p7 = facc0[base + 7];
      } else {
        p0 = facc1[base + 0]; p1 = facc1[base + 1]; p2 = facc1[base + 2]; p3 = facc1[base + 3];
        p4 = facc1[base + 4]; p5 = facc1[base + 5]; p6 = facc1[base + 6]; p7 = facc1[base + 7];
      }
      unsigned P0w0 = cvtpk(p0, p1), P0w1 = cvtpk(p2, p3);
      unsigned P1w0 = cvtpk(p4, p5), P1w1 = cvtpk(p6, p7);
      unsigned x0 = (unsigned)__shfl_xor((int)P0w0, 32);
      unsigned x1 = (unsigned)__shfl_xor((int)P0w1, 32);
      unsigned y0 = (unsigned)__shfl_xor((int)P1w0, 32);
      unsigned y1 = (unsigned)__shfl_xor((int)P1w1, 32);
      union { u32x4 u; short8 s8; } pf;
      pf.u[0] = hi ? y0 : P0w0;
      pf.u[1] = hi ? y1 : P0w1;
      pf.u[2] = hi ? P1w0 : x0;
      pf.u[3] = hi ? P1w1 : x1;
      int slot = (s << 1) | hi;
      #pragma unroll
      for (int n = 0; n < 4; n++) {
        int rg = n * 32 + l31;
        short8 gf = *reinterpret_cast<const short8*>(
            gb + rg * 128 + ((slot ^ (rg & 7)) * 16));
        acc[n] = MFMA32(pf.s8, gf, acc[n]);
      }
    }
    __builtin_amdgcn_s_setprio(0);
  }

  // ---- in-block merge of the two kv halves ----
  float lsum = lpart + __shfl_xor(lpart, 32);
  if (lane < 32) { ml[wave][l31][0] = mrun; ml[wave][l31][1] = lsum; }
  __syncthreads();
  float mo = ml[wave ^ 4][l31][0];
  float lo = ml[wave ^ 4][l31][1];
  float M = fmaxf(mrun, mo);
  float e0 = __expf(mrun - M), e1 = __expf(mo - M);
  float wown = e0 / (e0 * lsum + e1 * lo);   // normalized weight for own partial
  #pragma unroll
  for (int reg = 0; reg < 16; reg++) {
    int qr = (reg & 3) + 8 * (reg >> 2) + 4 * hi;
    float wr = __shfl(wown, qr);
    #pragma unroll
    for (int n = 0; n < 4; n++) acc[n][reg] *= wr;
  }
  float* mb = (float*)(lds + wq * 16384);    // 16KB per pair, overlays phi bufs
  if (zw == 1) {
    #pragma unroll
    for (int n = 0; n < 4; n++)
      #pragma unroll
      for (int reg = 0; reg < 16; reg++) {
        int qrow = (reg & 3) + 8 * (reg >> 2) + 4 * hi;
        mb[qrow * 128 + n * 32 + l31] = acc[n][reg];
      }
  }
  __syncthreads();
  if (zw == 0) {
    #pragma unroll
    for (int n = 0; n < 4; n++)
      #pragma unroll
      for (int reg = 0; reg < 16; reg++) {
        int qrow = (reg & 3) + 8 * (reg >> 2) + 4 * hi;
        float v = acc[n][reg] + mb[qrow * 128 + n * 32 + l31];
        y[((size_t)b * 4096 + q0 + wq * 32 + qrow) * 128 + n * 32 + l31] = f2bf(v);
      }
  }
}

// ---------------------------------------------------------------------------
// wy = w_w . y + bias, BN (eval), + x -> out fp32 [b][256][4096]
// 512 threads, 8 waves x 32 co, 128-q tiles, grid (32,8) = 256.
// ---------------------------------------------------------------------------
__global__ __launch_bounds__(512) void wconv_bn(
    const short* __restrict__ yb, const short* __restrict__ ww,
    const float* __restrict__ wb,
    const float* __restrict__ gamma, const float* __restrict__ beta,
    const float* __restrict__ mean, const float* __restrict__ var,
    const float* __restrict__ x, float* __restrict__ out)
{
  __shared__ short y_s[128][136];
  __shared__ float sc_s[256];
  __shared__ float sh_s[256];

  const int b = blockIdx.y;
  const int q0 = blockIdx.x * 128;
  const int tid = threadIdx.x;
  const int wave = tid >> 6, lane = tid & 63;
  const int lr = lane & 15, lg = lane >> 4;

  {
    int r = tid >> 2, c0 = (tid & 3) * 32;
    const short8* src = reinterpret_cast<const short8*>(
        yb + ((size_t)(b * 4096 + q0 + r)) * 128 + c0);
    short8* dst = reinterpret_cast<short8*>(&y_s[r][c0]);
    #pragma unroll
    for (int j = 0; j < 4; j++) dst[j] = src[j];
    if (tid < 256) {
      float s = gamma[tid] * rsqrtf(var[tid] + 1e-5f);
      sc_s[tid] = s;
      sh_s[tid] = (wb[tid] - mean[tid]) * s + beta[tid];
    }
  }
  __syncthreads();

  f32x4 acc[2][8];
  #pragma unroll
  for (int m = 0; m < 2; m++)
    #pragma unroll
    for (int n = 0; n < 8; n++) acc[m][n] = (f32x4)0.0f;

  #pragma unroll
  for (int kk = 0; kk < 4; kk++) {
    short8 af[2], bfr[8];
    #pragma unroll
    for (int m = 0; m < 2; m++)
      af[m] = *reinterpret_cast<const short8*>(
          ww + (size_t)(wave * 32 + m * 16 + lr) * 128 + kk * 32 + lg * 8);
    #pragma unroll
    for (int n = 0; n < 8; n++)
      bfr[n] = *reinterpret_cast<const short8*>(&y_s[n * 16 + lr][kk * 32 + lg * 8]);
    #pragma unroll
    for (int m = 0; m < 2; m++)
      #pragma unroll
      for (int n = 0; n < 8; n++)
        acc[m][n] = MFMA16(af[m], bfr[n], acc[m][n]);
  }

  #pragma unroll
  for (int m = 0; m < 2; m++) {
    #pragma unroll
    for (int n = 0; n < 8; n++) {
      #pragma unroll
      for (int r = 0; r < 4; r++) {
        int co = wave * 32 + m * 16 + lg * 4 + r;
        int q = q0 + n * 16 + lr;
        size_t oidx = ((size_t)b * 256 + co) * 4096 + q;
        float v = acc[m][n][r] * sc_s[co] + sh_s[co];
        out[oidx] = v + x[oidx];
      }
    }
  }
}

// ---------------------------------------------------------------------------
extern "C" void kernel_launch(void* const* d_in, const int* in_sizes, int n_in,
                              void* d_out, int out_size, void* d_ws, size_t ws_size,
                              hipStream_t stream)
{
  const float* x    = (const float*)d_in[0];
  const float* nb   = (const float*)d_in[1];
  const float* g_w  = (const float*)d_in[2];
  const float* g_b  = (const float*)d_in[3];
  const float* th_w = (const float*)d_in[4];
  const float* th_b = (const float*)d_in[5];
  const float* ph_w = (const float*)d_in[6];
  const float* ph_b = (const float*)d_in[7];
  const float* w_w  = (const float*)d_in[8];
  const float* w_b  = (const float*)d_in[9];
  const float* gam  = (const float*)d_in[10];
  const float* bet  = (const float*)d_in[11];
  const float* mu   = (const float*)d_in[12];
  const float* var  = (const float*)d_in[13];
  float* out = (float*)d_out;

  char* ws = (char*)d_ws;
  short* theta_full = (short*)(ws);                        // 8 MB  [b][4096][128]
  short* yb         = (short*)(ws + (size_t)(8u << 20));   // 8 MB  [b][4096][128]
  short* phi_kc     = (short*)(ws + (size_t)(16u << 20));  // 2 MB  [b][1024][128]
  short* g_ck       = (short*)(ws + (size_t)(18u << 20));  // 2 MB  [b][128][1024]
  short* wts        = (short*)(ws + (size_t)(20u << 20));  // 256KB: th, ph, g, w
  short* th_wb = wts;
  short* ph_wb = wts + 32768;
  short* g_wb  = wts + 2 * 32768;
  short* w_wb  = wts + 3 * 32768;

  cvt_w<<<dim3(32, 4), 256, 0, stream>>>(th_w, ph_w, g_w, w_w, wts);
  conv_all<<<dim3(32, 8, 2), 512, 0, stream>>>(nb, x, th_wb, th_b, ph_wb, ph_b,
                                               g_wb, g_b, theta_full, phi_kc, g_ck);
  attn<<<dim3(32, 8), 512, 0, stream>>>(theta_full, phi_kc, g_ck, yb);
  wconv_bn<<<dim3(32, 8), 512, 0, stream>>>(yb, w_wb, w_b, gam, bet, mu, var, x, out);
}

// Round 13
// 75.202 us; speedup vs baseline: 1.5840x; 1.0955x over previous
//
#include <hip/hip_runtime.h>

typedef __attribute__((ext_vector_type(8))) short short8;
typedef __attribute__((ext_vector_type(4))) short short4v;
typedef __attribute__((ext_vector_type(4))) float f32x4;
typedef __attribute__((ext_vector_type(16))) float f32x16;
typedef __attribute__((ext_vector_type(4))) unsigned u32x4;

#define LOG2E 1.4426950408889634f

__device__ __forceinline__ float bf2f(short s) {
  union { unsigned u; float f; } cv;
  cv.u = ((unsigned)(unsigned short)s) << 16;
  return cv.f;
}
__device__ __forceinline__ short f2bf(float f) {
  union { float f; unsigned u; } cv;
  cv.f = f;
  unsigned r = (cv.u + 0x7fffu + ((cv.u >> 16) & 1u)) >> 16;
  return (short)(unsigned short)r;
}
// packed RNE f32x2 -> bf16x2 (lo = a, hi = b) in one VALU op
__device__ __forceinline__ unsigned cvtpk(float a, float b) {
  unsigned r;
  asm("v_cvt_pk_bf16_f32 %0, %1, %2" : "=v"(r) : "v"(a), "v"(b));
  return r;
}
// raw v_exp_f32: 2^x
__device__ __forceinline__ float fexp2(float x) {
  float r;
  asm("v_exp_f32 %0, %1" : "=v"(r) : "v"(x));
  return r;
}
// async global->LDS, 16B/lane, lane i lands at ldsbase + i*16
__device__ __forceinline__ void load_lds16(const void* g, void* l) {
  __builtin_amdgcn_global_load_lds(
      (const __attribute__((address_space(1))) void*)g,
      (__attribute__((address_space(3))) void*)l, 16, 0, 0);
}

#define MFMA16(a, b, c) __builtin_amdgcn_mfma_f32_16x16x32_bf16((a), (b), (c), 0, 0, 0)
#define MFMA32(a, b, c) __builtin_amdgcn_mfma_f32_32x32x16_bf16((a), (b), (c), 0, 0, 0)

// ---------------------------------------------------------------------------
// convert fp32 weight matrices -> bf16 workspace. 4 matrices x 32768 elems.
// ---------------------------------------------------------------------------
__global__ __launch_bounds__(256) void cvt_w(
    const float* __restrict__ s0, const float* __restrict__ s1,
    const float* __restrict__ s2, const float* __restrict__ s3,
    short* __restrict__ d)
{
  const float* srcs[4] = {s0, s1, s2, s3};
  const float* s = srcs[blockIdx.y];
  int i = (blockIdx.x * 256 + threadIdx.x) * 4;
  f32x4 v = *reinterpret_cast<const f32x4*>(s + i);
  short4v o;
  #pragma unroll
  for (int j = 0; j < 4; j++) o[j] = f2bf(v[j]);
  *reinterpret_cast<short4v*>(d + (size_t)blockIdx.y * 32768 + i) = o;
}

// ---------------------------------------------------------------------------
// conv1x1 body (+ optional fused 2x2 maxpool epilogues).  Pixel<->M-row
// permutation puts a pooled cell's 4 pixels in one lane's f32x4 (exact).
// MODE: 0 full-res [b][p][o] SCALED by log2e (theta feeds exp2-domain attn);
//       1 pooled [b][kp][o]; 2 pooled-T [b][o][kp].
// ---------------------------------------------------------------------------
template <int NPROJ, int MODE1>
__device__ __forceinline__ void conv_body(
    short (*in_t)[40], short (*wt)[40],
    const float* __restrict__ in,
    const short* __restrict__ w0, const float* __restrict__ bias0,
    const short* __restrict__ w1, const float* __restrict__ bias1,
    short* __restrict__ out0, short* __restrict__ out1)
{
  const int b = blockIdx.y;
  const int p0 = blockIdx.x * 128;
  const int tid = threadIdx.x;
  const int wave = tid >> 6, lane = tid & 63;
  const int lr = lane & 15, lg = lane >> 4;

  const short* wsrc[2] = {w0, w1};

  f32x4 acc[NPROJ][8];
  #pragma unroll
  for (int pj = 0; pj < NPROJ; pj++)
    #pragma unroll
    for (int n = 0; n < 8; n++) acc[pj][n] = (f32x4)0.0f;

  for (int kc = 0; kc < 256; kc += 32) {
    __syncthreads();
    {
      int c = tid >> 4;                 // 0..31
      int pg = (tid & 15) * 8;          // global pixel group 0..120
      const float* src = in + ((size_t)(b * 256 + kc + c)) * 4096 + p0 + pg;
      f32x4 v0 = *reinterpret_cast<const f32x4*>(src);
      f32x4 v1 = *reinterpret_cast<const f32x4*>(src + 4);
      #pragma unroll
      for (int j = 0; j < 8; j++) {
        int p = pg + j;
        int a = ((p & 63) >> 1) * 4 + ((p >> 6) << 1) + (p & 1);
        float fv = (j < 4) ? v0[j] : v1[j - 4];
        in_t[a][c ^ ((((a >> 3) & 3)) << 3)] = f2bf(fv);
      }
    }
    if (tid < NPROJ * 128) {
      int pj = tid >> 7, o = tid & 127;
      const short8* src = reinterpret_cast<const short8*>(wsrc[pj] + (size_t)o * 256 + kc);
      int f = (o >> 3) & 3;
      #pragma unroll
      for (int gq = 0; gq < 4; gq++)
        *reinterpret_cast<short8*>(&wt[pj * 128 + o][(gq ^ f) * 8]) = src[gq];
    }
    __syncthreads();

    int arow = wave * 16 + lr;
    short8 afrag = *reinterpret_cast<const short8*>(
        &in_t[arow][(lg ^ ((arow >> 3) & 3)) * 8]);
    #pragma unroll
    for (int pj = 0; pj < NPROJ; pj++) {
      #pragma unroll
      for (int n = 0; n < 8; n++) {
        int brow = n * 16 + lr;
        short8 bfrag = *reinterpret_cast<const short8*>(
            &wt[pj * 128 + brow][(lg ^ ((brow >> 3) & 3)) * 8]);
        acc[pj][n] = MFMA16(afrag, bfrag, acc[pj][n]);
      }
    }
  }

  const float* bsrc[2] = {bias0, bias1};
  short* osrc[2] = {out0, out1};
  const int kp = blockIdx.x * 32 + wave * 4 + lg;
  #pragma unroll
  for (int pj = 0; pj < NPROJ; pj++) {
    const int mode = (pj == 0 && NPROJ == 2) ? 0 : MODE1;
    #pragma unroll
    for (int n = 0; n < 8; n++) {
      int o = n * 16 + lr;
      float bv = bsrc[pj][o];
      if (mode == 0) {
        #pragma unroll
        for (int r = 0; r < 4; r++) {
          int pix = (wave * 4 + lg) * 2 + (r & 1) + ((r >> 1) & 1) * 64;
          osrc[pj][((size_t)b * 4096 + p0 + pix) * 128 + o] =
              f2bf((acc[pj][n][r] + bv) * LOG2E);
        }
      } else {
        f32x4 v = acc[pj][n];
        float pv = fmaxf(fmaxf(v[0], v[1]), fmaxf(v[2], v[3])) + bv;
        if (mode == 1)
          osrc[pj][((size_t)b * 1024 + kp) * 128 + o] = f2bf(pv);
        else
          osrc[pj][((size_t)b * 128 + o) * 1024 + kp] = f2bf(pv);
      }
    }
  }
}

// fused conv dispatch: z=0 -> theta(full, xlog2e)+phi(pooled) from nb;
//                      z=1 -> g (pooled-T) from x.  2 blocks/CU.
__global__ __launch_bounds__(512, 4) void conv_all(
    const float* __restrict__ nb, const float* __restrict__ x,
    const short* __restrict__ th_w, const float* __restrict__ th_b,
    const short* __restrict__ ph_w, const float* __restrict__ ph_b,
    const short* __restrict__ g_w, const float* __restrict__ g_b,
    short* __restrict__ theta, short* __restrict__ phi_kc,
    short* __restrict__ g_ck)
{
  __shared__ short in_t[128][40];
  __shared__ short wt[256][40];
  if (blockIdx.z == 0)
    conv_body<2, 1>(in_t, wt, nb, th_w, th_b, ph_w, ph_b, theta, phi_kc);
  else
    conv_body<1, 2>(in_t, wt, x, g_w, g_b, nullptr, nullptr, g_ck, nullptr);
}

// ---------------------------------------------------------------------------
// FUSED flash attention + W-conv + BN + residual.
// Phase A (attn): in-block split-KV (waves 0-3 kv[0,512), 4-7 kv[512,1024)),
//   32x32 MFMA, gload_lds staging (pre-swizzled src), exp2 domain,
//   in-register P.  Phase B: merge halves -> y tile bf16 in LDS ->
//   8-wave GEMM wy = w.y, BN, +x -> out fp32.
// LDS overlay discipline: ALL overlay writes (sc/sh, mb, y_s) occur only
// after the first post-loop barrier (all loop-phase LDS reads complete).
// Grid (32, 8) = 256 blocks, 512 threads.
// ---------------------------------------------------------------------------
__global__ __launch_bounds__(512) void attn_wconv(
    const short* __restrict__ theta, const short* __restrict__ phi,
    const short* __restrict__ g, const short* __restrict__ ww,
    const float* __restrict__ wb,
    const float* __restrict__ gamma, const float* __restrict__ beta,
    const float* __restrict__ mean, const float* __restrict__ var,
    const float* __restrict__ x, float* __restrict__ out)
{
  __shared__ char lds[131072];          // attn: phi bufs 0-64K, g bufs 64-128K
                                        // post: mb 0-64K, y_s @64K, sc/sh @112K
  __shared__ float ml[8][32][2];

  const int b = blockIdx.y;
  const int q0 = blockIdx.x * 128;
  const int tid = threadIdx.x;
  const int wave = tid >> 6, lane = tid & 63;
  const int l31 = lane & 31, hi = lane >> 5;
  const int zw = wave >> 2, wq = wave & 3;

  // theta B-fragments (theta pre-scaled by log2e)
  short8 ath[8];
  {
    const short* tq = theta + ((size_t)b * 4096 + q0 + wq * 32 + l31) * 128 + hi * 8;
    #pragma unroll
    for (int s = 0; s < 8; s++)
      ath[s] = *reinterpret_cast<const short8*>(tq + s * 16);
  }

  // gload_lds staging (pre-swizzled global src, linear LDS dest)
  const short* psrc[4];
  {
    int rb = wq * 16 + (lane >> 4), sl = lane & 15;
    #pragma unroll
    for (int i = 0; i < 4; i++) {
      int r = rb + i * 4;
      psrc[i] = phi + ((size_t)b * 1024 + zw * 512 + r) * 128 + ((sl ^ (r & 15)) * 8);
    }
  }
  const short* gsrc[4];
  {
    int rb = wq * 32 + (lane >> 3), sl = lane & 7;
    #pragma unroll
    for (int i = 0; i < 4; i++) {
      int r = rb + i * 8;
      gsrc[i] = g + ((size_t)b * 128 + r) * 1024 + zw * 512 + ((sl ^ (r & 7)) * 8);
    }
  }

  float mrun = -1e30f, lpart = 0.0f;
  f32x16 acc[4];
  #pragma unroll
  for (int n = 0; n < 4; n++) acc[n] = (f32x16)0.0f;

  {
    char* pb = lds + zw * 16384 + wq * 4096;
    char* gb = lds + 65536 + zw * 16384 + wq * 4096;
    #pragma unroll
    for (int i = 0; i < 4; i++) {
      load_lds16(psrc[i], pb + i * 1024);
      load_lds16(gsrc[i], gb + i * 1024);
    }
  }

  for (int t = 0; t < 8; t++) {
    __syncthreads();
    char* pb = lds + ((t & 1) * 2 + zw) * 16384;
    char* gb = lds + 65536 + ((t & 1) * 2 + zw) * 16384;

    if (t < 7) {
      char* pb2 = lds + (((t + 1) & 1) * 2 + zw) * 16384 + wq * 4096;
      char* gb2 = lds + 65536 + (((t + 1) & 1) * 2 + zw) * 16384 + wq * 4096;
      #pragma unroll
      for (int i = 0; i < 4; i++) {
        load_lds16(psrc[i] + (t + 1) * 8192, pb2 + i * 1024);
        load_lds16(gsrc[i] + (t + 1) * 64, gb2 + i * 1024);
      }
    }

    // QK^T (S' in log2 units)
    f32x16 facc0 = (f32x16)0.0f, facc1 = (f32x16)0.0f;
    __builtin_amdgcn_s_setprio(1);
    #pragma unroll
    for (int s = 0; s < 8; s++) {
      int slot = (s << 1) | hi;
      short8 pf0 = *reinterpret_cast<const short8*>(
          pb + l31 * 256 + ((slot ^ (l31 & 15)) * 16));
      short8 pf1 = *reinterpret_cast<const short8*>(
          pb + (32 + l31) * 256 + ((slot ^ (l31 & 15)) * 16));
      facc0 = MFMA32(pf0, ath[s], facc0);
      facc1 = MFMA32(pf1, ath[s], facc1);
    }
    __builtin_amdgcn_s_setprio(0);

    // online softmax in exp2 domain; depth-5 trees
    float mv[16];
    #pragma unroll
    for (int r = 0; r < 16; r++) mv[r] = fmaxf(facc0[r], facc1[r]);
    #pragma unroll
    for (int s = 8; s >= 1; s >>= 1)
      #pragma unroll
      for (int r = 0; r < s; r++) mv[r] = fmaxf(mv[r], mv[r + s]);
    float m = fmaxf(mv[0], __shfl_xor(mv[0], 32));

    if (__any(m - mrun > 14.0f)) {
      float mn = fmaxf(mrun, m);
      float sc = fexp2(mrun - mn);
      mrun = mn;
      lpart *= sc;
      #pragma unroll
      for (int reg = 0; reg < 16; reg++) {
        int qr = (reg & 3) + 8 * (reg >> 2) + 4 * hi;
        float sr = __shfl(sc, qr);
        #pragma unroll
        for (int n = 0; n < 4; n++) acc[n][reg] *= sr;
      }
    }
    #pragma unroll
    for (int r = 0; r < 16; r++) facc0[r] = fexp2(facc0[r] - mrun);
    #pragma unroll
    for (int r = 0; r < 16; r++) facc1[r] = fexp2(facc1[r] - mrun);
    {
      float sv[16];
      #pragma unroll
      for (int r = 0; r < 16; r++) sv[r] = facc0[r] + facc1[r];
      #pragma unroll
      for (int s = 8; s >= 1; s >>= 1)
        #pragma unroll
        for (int r = 0; r < s; r++) sv[r] += sv[r + s];
      lpart += sv[0];
    }

    // PV with in-register P assembly
    __builtin_amdgcn_s_setprio(1);
    #pragma unroll
    for (int s = 0; s < 4; s++) {
      const int base = (s & 1) * 8;
      float p0, p1, p2, p3, p4, p5, p6, p7;
      if (s < 2) {
        p0 = facc0[base + 0]; p1 = facc0[base + 1]; p2 = facc0[base + 2]; p3 = facc0[base + 3];
        p4 = facc0[base + 4]; p5 = facc0[base + 5]; p6 = facc0[base + 6]; p7 = facc0[base + 7];
      } else {
        p0 = facc1[base + 0]; p1 = facc1[base + 1]; p2 = facc1[base + 2]; p3 = facc1[base + 3];
        p4 = facc1[base + 4]; p5 = facc1[base + 5]; p6 = facc1[base + 6]; p7 = facc1[base + 7];
      }
      unsigned P0w0 = cvtpk(p0, p1), P0w1 = cvtpk(p2, p3);
      unsigned P1w0 = cvtpk(p4, p5), P1w1 = cvtpk(p6, p7);
      unsigned x0 = (unsigned)__shfl_xor((int)P0w0, 32);
      unsigned x1 = (unsigned)__shfl_xor((int)P0w1, 32);
      unsigned y0 = (unsigned)__shfl_xor((int)P1w0, 32);
      unsigned y1 = (unsigned)__shfl_xor((int)P1w1, 32);
      union { u32x4 u; short8 s8; } pf;
      pf.u[0] = hi ? y0 : P0w0;
      pf.u[1] = hi ? y1 : P0w1;
      pf.u[2] = hi ? P1w0 : x0;
      pf.u[3] = hi ? P1w1 : x1;
      int slot = (s << 1) | hi;
      #pragma unroll
      for (int n = 0; n < 4; n++) {
        int rg = n * 32 + l31;
        short8 gf = *reinterpret_cast<const short8*>(
            gb + rg * 128 + ((slot ^ (rg & 7)) * 16));
        acc[n] = MFMA32(pf.s8, gf, acc[n]);
      }
    }
    __builtin_amdgcn_s_setprio(0);
  }

  // ---- Phase B ----
  float lsum = lpart + __shfl_xor(lpart, 32);
  if (lane < 32) { ml[wave][l31][0] = mrun; ml[wave][l31][1] = lsum; }
  __syncthreads();   // ALL loop-phase LDS reads complete; overlays now safe

  float* sc_s = (float*)(lds + 114688);
  float* sh_s = (float*)(lds + 118784);
  if (tid < 256) {
    float s = gamma[tid] * rsqrtf(var[tid] + 1e-5f);
    sc_s[tid] = s;
    sh_s[tid] = (wb[tid] - mean[tid]) * s + beta[tid];
  }

  float mo = ml[wave ^ 4][l31][0];
  float lo = ml[wave ^ 4][l31][1];
  float M = fmaxf(mrun, mo);
  float e0 = fexp2(mrun - M), e1 = fexp2(mo - M);
  float wown = e0 / (e0 * lsum + e1 * lo);
  #pragma unroll
  for (int reg = 0; reg < 16; reg++) {
    int qr = (reg & 3) + 8 * (reg >> 2) + 4 * hi;
    float wr = __shfl(wown, qr);
    #pragma unroll
    for (int n = 0; n < 4; n++) acc[n][reg] *= wr;
  }
  float* mb = (float*)(lds + wq * 16384);    // fp32 exchange, overlays phi bufs
  if (zw == 1) {
    #pragma unroll
    for (int n = 0; n < 4; n++)
      #pragma unroll
      for (int reg = 0; reg < 16; reg++) {
        int qrow = (reg & 3) + 8 * (reg >> 2) + 4 * hi;
        mb[qrow * 128 + n * 32 + l31] = acc[n][reg];
      }
  }
  __syncthreads();
  short* y_s = (short*)(lds + 65536);        // [128][136] bf16, overlays g bufs
  if (zw == 0) {
    #pragma unroll
    for (int n = 0; n < 4; n++)
      #pragma unroll
      for (int reg = 0; reg < 16; reg++) {
        int qrow = (reg & 3) + 8 * (reg >> 2) + 4 * hi;
        float v = acc[n][reg] + mb[qrow * 128 + n * 32 + l31];
        y_s[(wq * 32 + qrow) * 136 + n * 32 + l31] = f2bf(v);
      }
  }
  __syncthreads();

  // W-GEMM: 8 waves x 32 co over this block's 128 q
  const int lr = lane & 15, lg = lane >> 4;
  f32x4 acc2[2][8];
  #pragma unroll
  for (int mm = 0; mm < 2; mm++)
    #pragma unroll
    for (int n = 0; n < 8; n++) acc2[mm][n] = (f32x4)0.0f;

  #pragma unroll
  for (int kk = 0; kk < 4; kk++) {
    short8 af[2], bfr[8];
    #pragma unroll
    for (int mm = 0; mm < 2; mm++)
      af[mm] = *reinterpret_cast<const short8*>(
          ww + (size_t)(wave * 32 + mm * 16 + lr) * 128 + kk * 32 + lg * 8);
    #pragma unroll
    for (int n = 0; n < 8; n++)
      bfr[n] = *reinterpret_cast<const short8*>(
          &y_s[(n * 16 + lr) * 136 + kk * 32 + lg * 8]);
    #pragma unroll
    for (int mm = 0; mm < 2; mm++)
      #pragma unroll
      for (int n = 0; n < 8; n++)
        acc2[mm][n] = MFMA16(af[mm], bfr[n], acc2[mm][n]);
  }

  #pragma unroll
  for (int mm = 0; mm < 2; mm++) {
    #pragma unroll
    for (int n = 0; n < 8; n++) {
      #pragma unroll
      for (int r = 0; r < 4; r++) {
        int co = wave * 32 + mm * 16 + lg * 4 + r;
        int q = q0 + n * 16 + lr;
        size_t oidx = ((size_t)b * 256 + co) * 4096 + q;
        float v = acc2[mm][n][r] * sc_s[co] + sh_s[co];
        out[oidx] = v + x[oidx];
      }
    }
  }
}

// ---------------------------------------------------------------------------
extern "C" void kernel_launch(void* const* d_in, const int* in_sizes, int n_in,
                              void* d_out, int out_size, void* d_ws, size_t ws_size,
                              hipStream_t stream)
{
  const float* x    = (const float*)d_in[0];
  const float* nb   = (const float*)d_in[1];
  const float* g_w  = (const float*)d_in[2];
  const float* g_b  = (const float*)d_in[3];
  const float* th_w = (const float*)d_in[4];
  const float* th_b = (const float*)d_in[5];
  const float* ph_w = (const float*)d_in[6];
  const float* ph_b = (const float*)d_in[7];
  const float* w_w  = (const float*)d_in[8];
  const float* w_b  = (const float*)d_in[9];
  const float* gam  = (const float*)d_in[10];
  const float* bet  = (const float*)d_in[11];
  const float* mu   = (const float*)d_in[12];
  const float* var  = (const float*)d_in[13];
  float* out = (float*)d_out;

  char* ws = (char*)d_ws;
  short* theta_full = (short*)(ws);                        // 8 MB  [b][4096][128]
  short* phi_kc     = (short*)(ws + (size_t)(8u << 20));   // 2 MB  [b][1024][128]
  short* g_ck       = (short*)(ws + (size_t)(10u << 20));  // 2 MB  [b][128][1024]
  short* wts        = (short*)(ws + (size_t)(12u << 20));  // 256KB: th, ph, g, w
  short* th_wb = wts;
  short* ph_wb = wts + 32768;
  short* g_wb  = wts + 2 * 32768;
  short* w_wb  = wts + 3 * 32768;

  cvt_w<<<dim3(32, 4), 256, 0, stream>>>(th_w, ph_w, g_w, w_w, wts);
  conv_all<<<dim3(32, 8, 2), 512, 0, stream>>>(nb, x, th_wb, th_b, ph_wb, ph_b,
                                               g_wb, g_b, theta_full, phi_kc, g_ck);
  attn_wconv<<<dim3(32, 8), 512, 0, stream>>>(theta_full, phi_kc, g_ck, w_wb, w_b,
                                              gam, bet, mu, var, x, out);
}